// Round 6
// baseline (838.871 us; speedup 1.0000x reference)
//
#include <hip/hip_runtime.h>

#define LRELU(x) ((x) > 0.0f ? (x) : 0.01f * (x))
#define UAF __uint_as_float

__device__ inline uint pack_bf16_rne(float x, float y) {
    uint lo = __float_as_uint(x);
    uint hi = __float_as_uint(y);
    lo = (lo + 0x7fffu + ((lo >> 16) & 1u)) >> 16;
    hi = (hi + 0x7fffu + ((hi >> 16) & 1u)) & 0xffff0000u;
    return lo | hi;
}

__global__ void zero_kernel(float* p, int n) {
    int i = blockIdx.x * blockDim.x + threadIdx.x;
    if (i < n) p[i] = 0.0f;
}

// ---------- CSR build ----------
__global__ void hist_kernel(const int* __restrict__ dst, int* __restrict__ cnt, int E) {
    int e = blockIdx.x * blockDim.x + threadIdx.x;
    if (e < E) atomicAdd(&cnt[dst[e]], 1);
}

__global__ __launch_bounds__(256) void scan1_kernel(const int* __restrict__ cnt,
                                                    int* __restrict__ ptr,
                                                    int* __restrict__ blksum, int n) {
    __shared__ int sh[256];
    int t = threadIdx.x;
    int base = blockIdx.x * 1024 + t * 4;
    int c0 = (base + 0 < n) ? cnt[base + 0] : 0;
    int c1 = (base + 1 < n) ? cnt[base + 1] : 0;
    int c2 = (base + 2 < n) ? cnt[base + 2] : 0;
    int c3 = (base + 3 < n) ? cnt[base + 3] : 0;
    int tsum = c0 + c1 + c2 + c3;
    sh[t] = tsum;
    __syncthreads();
    for (int o = 1; o < 256; o <<= 1) {
        int v = (t >= o) ? sh[t - o] : 0;
        __syncthreads();
        sh[t] += v;
        __syncthreads();
    }
    int excl = sh[t] - tsum;
    if (base + 0 < n) ptr[base + 0] = excl;
    excl += c0;
    if (base + 1 < n) ptr[base + 1] = excl;
    excl += c1;
    if (base + 2 < n) ptr[base + 2] = excl;
    excl += c2;
    if (base + 3 < n) ptr[base + 3] = excl;
    if (t == 255) blksum[blockIdx.x] = sh[255];
}

__global__ __launch_bounds__(256) void scan2_kernel(int* __restrict__ blksum, int nb) {
    __shared__ int sh[256];
    int t = threadIdx.x;
    int v0 = (t < nb) ? blksum[t] : 0;
    sh[t] = v0;
    __syncthreads();
    for (int o = 1; o < 256; o <<= 1) {
        int v = (t >= o) ? sh[t - o] : 0;
        __syncthreads();
        sh[t] += v;
        __syncthreads();
    }
    if (t < nb) blksum[t] = sh[t] - v0;
}

__global__ void scan3_kernel(int* __restrict__ ptr, const int* __restrict__ blksum,
                             int* __restrict__ cursor, int n) {
    int i = blockIdx.x * blockDim.x + threadIdx.x;
    if (i >= n) return;
    int p = ptr[i] + blksum[i >> 10];
    ptr[i] = p;
    cursor[i] = p;
}

// nt store: avoid L2 line-bounce on random 4B writes (r5: 105MB HBM WRITE for 6.4MB array)
__global__ void fill_kernel(const int* __restrict__ src, const int* __restrict__ dst,
                            int* __restrict__ cursor, int* __restrict__ nbr, int E) {
    int e = blockIdx.x * blockDim.x + threadIdx.x;
    if (e >= E) return;
    int d = dst[e];
    int pos = atomicAdd(&cursor[d], 1);
    __builtin_nontemporal_store(src[e], &nbr[pos]);
}

// ---------- fp32 -> bf16 (RNE) feature table (layer 0 input only) ----------
__global__ __launch_bounds__(256) void to_bf16_kernel(const float* __restrict__ in,
                                                      uint* __restrict__ table, int n8) {
    int i = blockIdx.x * blockDim.x + threadIdx.x;
    if (i >= n8) return;
    float4 a = *(const float4*)&in[(size_t)i * 8];
    float4 b = *(const float4*)&in[(size_t)i * 8 + 4];
    uint4 p = make_uint4(pack_bf16_rne(a.x, a.y), pack_bf16_rne(a.z, a.w),
                         pack_bf16_rne(b.x, b.y), pack_bf16_rne(b.z, b.w));
    *(uint4*)&table[(size_t)i * 4] = p;
}

// ---------- fused GIN aggregation + Linear(64->64) + col-stats ----------
// table holds bf16 features (raw pre-BN for ACT=true); half-wave gathers one node,
// lane sl owns features (2sl, 2sl+1); BN-affine+LeakyReLU applied per gathered element.
template <bool ACT>
__global__ __launch_bounds__(256, 4) void gin_gemm_kernel(
    const ushort* __restrict__ table, const int* __restrict__ ptr,
    const int* __restrict__ cnt, const int* __restrict__ nbr,
    const float* __restrict__ eps_gin, int layer, const float* __restrict__ scale,
    const float* __restrict__ shift, const float* __restrict__ W,
    const float* __restrict__ bias, float* __restrict__ out, float* __restrict__ sums,
    int nrows) {
    __shared__ float inT[64][68];  // [k][row]
    __shared__ float ws[64][64];   // [k][col]
    int t = threadIdx.x;
    int row0 = blockIdx.x * 64;
    int hw = t >> 5;  // half-wave 0..7
    int sl = t & 31;
    float ep = 1.0f + eps_gin[layer];
    float sc0 = 1.0f, sh0 = 0.0f, sc1 = 1.0f, sh1 = 0.0f;
    if (ACT) {
        sc0 = scale[2 * sl + 0];
        sh0 = shift[2 * sl + 0];
        sc1 = scale[2 * sl + 1];
        sh1 = shift[2 * sl + 1];
    }

    // gather-stage 8 nodes per half-wave
    for (int q = 0; q < 8; q++) {
        int r = hw * 8 + q;
        int gr = row0 + r;
        float a0 = 0.0f, a1 = 0.0f;
        if (gr < nrows) {
            int start = ptr[gr];
            int deg = cnt[gr];
            int j = 0;
            for (; j + 1 < deg; j += 2) {
                int nA = nbr[start + j];
                int nB = nbr[start + j + 1];
                uint vA = *(const uint*)(table + (size_t)nA * 64 + sl * 2);
                uint vB = *(const uint*)(table + (size_t)nB * 64 + sl * 2);
                float fA0 = UAF(vA << 16), fA1 = UAF(vA & 0xffff0000u);
                float fB0 = UAF(vB << 16), fB1 = UAF(vB & 0xffff0000u);
                if (ACT) {
                    fA0 = LRELU(fA0 * sc0 + sh0);
                    fA1 = LRELU(fA1 * sc1 + sh1);
                    fB0 = LRELU(fB0 * sc0 + sh0);
                    fB1 = LRELU(fB1 * sc1 + sh1);
                }
                a0 += fA0 + fB0;
                a1 += fA1 + fB1;
            }
            if (j < deg) {
                int nA = nbr[start + j];
                uint vA = *(const uint*)(table + (size_t)nA * 64 + sl * 2);
                float fA0 = UAF(vA << 16), fA1 = UAF(vA & 0xffff0000u);
                if (ACT) {
                    fA0 = LRELU(fA0 * sc0 + sh0);
                    fA1 = LRELU(fA1 * sc1 + sh1);
                }
                a0 += fA0;
                a1 += fA1;
            }
            uint vs = *(const uint*)(table + (size_t)gr * 64 + sl * 2);
            float s0 = UAF(vs << 16), s1 = UAF(vs & 0xffff0000u);
            if (ACT) {
                s0 = LRELU(s0 * sc0 + sh0);
                s1 = LRELU(s1 * sc1 + sh1);
            }
            a0 += ep * s0;
            a1 += ep * s1;
        }
        inT[2 * sl + 0][r] = a0;
        inT[2 * sl + 1][r] = a1;
    }
    // stage W (64x64)
    for (int i = 0; i < 4; i++) {
        int f = t + 256 * i;
        int k = f >> 4;
        int c4 = f & 15;
        *(float4*)&ws[k][c4 * 4] = *(const float4*)&W[(size_t)k * 64 + c4 * 4];
    }
    __syncthreads();

    int rg = t >> 4;
    int cg = t & 15;
    int r0 = rg * 4;
    int c0 = cg * 4;
    float acc[4][4];
#pragma unroll
    for (int r = 0; r < 4; r++)
#pragma unroll
        for (int c = 0; c < 4; c++) acc[r][c] = 0.0f;

#pragma unroll 16
    for (int k = 0; k < 64; k++) {
        float4 a = *(const float4*)&inT[k][r0];
        float ar[4] = {a.x, a.y, a.z, a.w};
        float4 w4 = *(const float4*)&ws[k][c0];
        float wr[4] = {w4.x, w4.y, w4.z, w4.w};
#pragma unroll
        for (int r = 0; r < 4; r++)
#pragma unroll
            for (int c = 0; c < 4; c++) acc[r][c] += ar[r] * wr[c];
    }

    float ps[4], ps2[4];
#pragma unroll
    for (int c = 0; c < 4; c++) ps[c] = ps2[c] = 0.0f;
    float4 bv = *(const float4*)&bias[c0];
#pragma unroll
    for (int r = 0; r < 4; r++) {
        int gr = row0 + r0 + r;
        if (gr < nrows) {
            float4 o = make_float4(acc[r][0] + bv.x, acc[r][1] + bv.y, acc[r][2] + bv.z,
                                   acc[r][3] + bv.w);
            *(float4*)&out[(size_t)gr * 64 + c0] = o;
            ps[0] += o.x;
            ps2[0] += o.x * o.x;
            ps[1] += o.y;
            ps2[1] += o.y * o.y;
            ps[2] += o.z;
            ps2[2] += o.z * o.z;
            ps[3] += o.w;
            ps2[3] += o.w * o.w;
        }
    }

    __syncthreads();
    float* red = &inT[0][0];
    float* red2 = red + 16 * 64;
    *(float4*)&red[rg * 64 + c0] = *(float4*)&ps[0];
    *(float4*)&red2[rg * 64 + c0] = *(float4*)&ps2[0];
    __syncthreads();
    if (t < 64) {
        float s = 0.0f, s2 = 0.0f;
#pragma unroll
        for (int j = 0; j < 16; j++) {
            s += red[j * 64 + t];
            s2 += red2[j * 64 + t];
        }
        atomicAdd(&sums[t], s);
        atomicAdd(&sums[64 + t], s2);
    }
}

__global__ void finalize_kernel(const float* __restrict__ sums, const float* __restrict__ g,
                                const float* __restrict__ be, float* __restrict__ scale,
                                float* __restrict__ shift, int C, float invN) {
    int d = threadIdx.x;
    if (d >= C) return;
    float mean = sums[d] * invN;
    float var = sums[C + d] * invN - mean * mean;
    float sc = g[d] * rsqrtf(var + 1e-5f);
    scale[d] = sc;
    shift[d] = be[d] - mean * sc;
}

// out = act(in) @ W + bias; OUTBF16: write RNE-packed bf16 table (raw, stats from fp32)
template <int COLS, bool OUTBF16>
__global__ __launch_bounds__(256, 4) void gemm_kernel(const float* __restrict__ in,
                                                      const float* __restrict__ W,
                                                      const float* __restrict__ bias,
                                                      const float* __restrict__ scale,
                                                      const float* __restrict__ shift,
                                                      float* __restrict__ out,
                                                      uint* __restrict__ tout,
                                                      float* __restrict__ sums, int nrows) {
    __shared__ float inT[64][68];
    __shared__ float ws[64][COLS];
    int t = threadIdx.x;
    int row0 = blockIdx.x * 64;

    for (int i = 0; i < 4; i++) {
        int f = t + 256 * i;
        int r = f >> 4;
        int ch = f & 15;
        int gr = row0 + r;
        float4 v = make_float4(0.f, 0.f, 0.f, 0.f);
        if (gr < nrows) v = *(const float4*)&in[(size_t)gr * 64 + ch * 4];
        if (scale) {
            int d = ch * 4;
            v.x = LRELU(v.x * scale[d + 0] + shift[d + 0]);
            v.y = LRELU(v.y * scale[d + 1] + shift[d + 1]);
            v.z = LRELU(v.z * scale[d + 2] + shift[d + 2]);
            v.w = LRELU(v.w * scale[d + 3] + shift[d + 3]);
        }
        inT[ch * 4 + 0][r] = v.x;
        inT[ch * 4 + 1][r] = v.y;
        inT[ch * 4 + 2][r] = v.z;
        inT[ch * 4 + 3][r] = v.w;
    }
    for (int i = 0; i < COLS / 16; i++) {
        int f = t + 256 * i;
        int k = f / (COLS / 4);
        int c4 = f % (COLS / 4);
        *(float4*)&ws[k][c4 * 4] = *(const float4*)&W[(size_t)k * COLS + c4 * 4];
    }
    __syncthreads();

    constexpr int NCH = COLS / 64;
    int rg = t >> 4;
    int cg = t & 15;
    int r0 = rg * 4;
    int c0 = cg * 4;
    float acc[4][NCH * 4];
#pragma unroll
    for (int r = 0; r < 4; r++)
#pragma unroll
        for (int c = 0; c < NCH * 4; c++) acc[r][c] = 0.0f;

#pragma unroll 16
    for (int k = 0; k < 64; k++) {
        float4 a = *(const float4*)&inT[k][r0];
        float ar[4] = {a.x, a.y, a.z, a.w};
#pragma unroll
        for (int jj = 0; jj < NCH; jj++) {
            float4 w4 = *(const float4*)&ws[k][c0 + jj * 64];
            float wr[4] = {w4.x, w4.y, w4.z, w4.w};
#pragma unroll
            for (int r = 0; r < 4; r++)
#pragma unroll
                for (int c = 0; c < 4; c++) acc[r][jj * 4 + c] += ar[r] * wr[c];
        }
    }

    float ps[NCH * 4], ps2[NCH * 4];
#pragma unroll
    for (int c = 0; c < NCH * 4; c++) ps[c] = ps2[c] = 0.0f;
#pragma unroll
    for (int r = 0; r < 4; r++) {
        int gr = row0 + r0 + r;
        if (gr < nrows) {
#pragma unroll
            for (int jj = 0; jj < NCH; jj++) {
                float4 bv = *(const float4*)&bias[c0 + jj * 64];
                float4 o = make_float4(acc[r][jj * 4 + 0] + bv.x, acc[r][jj * 4 + 1] + bv.y,
                                       acc[r][jj * 4 + 2] + bv.z, acc[r][jj * 4 + 3] + bv.w);
                if (OUTBF16) {
                    uint2 pk = make_uint2(pack_bf16_rne(o.x, o.y), pack_bf16_rne(o.z, o.w));
                    *(uint2*)&tout[(size_t)gr * 32 + (c0 >> 1)] = pk;
                } else {
                    *(float4*)&out[(size_t)gr * COLS + c0 + jj * 64] = o;
                }
                ps[jj * 4 + 0] += o.x;
                ps2[jj * 4 + 0] += o.x * o.x;
                ps[jj * 4 + 1] += o.y;
                ps2[jj * 4 + 1] += o.y * o.y;
                ps[jj * 4 + 2] += o.z;
                ps2[jj * 4 + 2] += o.z * o.z;
                ps[jj * 4 + 3] += o.w;
                ps2[jj * 4 + 3] += o.w * o.w;
            }
        }
    }

    if (sums == nullptr) return;

    __syncthreads();
    float* red = &inT[0][0];
    float* red2 = red + 16 * COLS;
#pragma unroll
    for (int jj = 0; jj < NCH; jj++) {
        *(float4*)&red[rg * COLS + c0 + jj * 64] = *(float4*)&ps[jj * 4];
        *(float4*)&red2[rg * COLS + c0 + jj * 64] = *(float4*)&ps2[jj * 4];
    }
    __syncthreads();
    if (t < COLS) {
        float s = 0.0f, s2 = 0.0f;
#pragma unroll
        for (int j = 0; j < 16; j++) {
            s += red[j * COLS + t];
            s2 += red2[j * COLS + t];
        }
        atomicAdd(&sums[t], s);
        atomicAdd(&sums[COLS + t], s2);
    }
}

__global__ void head_out_kernel(const float* __restrict__ hf, const float* __restrict__ scale,
                                const float* __restrict__ shift, const float* __restrict__ Wf2,
                                const float* __restrict__ bf2, float* __restrict__ out,
                                int nrows) {
    int gtid = blockIdx.x * blockDim.x + threadIdx.x;
    int wid = gtid >> 6;
    int l = threadIdx.x & 63;
    if (wid >= nrows) return;
    float v0 = hf[(size_t)wid * 128 + l];
    float v1 = hf[(size_t)wid * 128 + 64 + l];
    v0 = LRELU(v0 * scale[l] + shift[l]);
    v1 = LRELU(v1 * scale[64 + l] + shift[64 + l]);
    float p = v0 * Wf2[l] + v1 * Wf2[64 + l];
    for (int o = 32; o > 0; o >>= 1) p += __shfl_down(p, o);
    if (l == 0) out[wid] = p + bf2[0];
}

extern "C" void kernel_launch(void* const* d_in, const int* in_sizes, int n_in, void* d_out,
                              int out_size, void* d_ws, size_t ws_size, hipStream_t stream) {
    const float* x = (const float*)d_in[0];
    const int* esrc = (const int*)d_in[1];
    const int* edst = (const int*)d_in[2];
    const float* W1 = (const float*)d_in[3];
    const float* b1 = (const float*)d_in[4];
    const float* g1 = (const float*)d_in[5];
    const float* be1 = (const float*)d_in[6];
    const float* W2 = (const float*)d_in[7];
    const float* b2 = (const float*)d_in[8];
    const float* eps_gin = (const float*)d_in[9];
    const float* g_bn = (const float*)d_in[10];
    const float* b_bn = (const float*)d_in[11];
    const float* Wf1 = (const float*)d_in[12];
    const float* bf1 = (const float*)d_in[13];
    const float* gf = (const float*)d_in[14];
    const float* bef = (const float*)d_in[15];
    const float* Wf2 = (const float*)d_in[16];
    const float* bf2 = (const float*)d_in[17];
    float* out = (float*)d_out;

    int N = in_sizes[0] / 64;
    int E = in_sizes[1];
    float invN = 1.0f / (float)N;

    float* ws = (float*)d_ws;
    size_t ND = (size_t)N * 64;
    // region A: bf16 table (first ND/2 floats) until layer-2 gemm2, then fp32 X
    float* A = ws;
    uint* table = (uint*)A;
    float* X = A;
    float* S1 = ws + ND;      // h1; later HF low half
    float* S2 = ws + 2 * ND;  // HF high half
    float* HF = S1;           // N x 128 spans S1+S2
    float* stats = ws + 3 * ND;
    int* ibase = (int*)(stats + 3072);
    int* cnt = ibase;
    int* ptr = ibase + N;
    int* cursor = ibase + 2 * N;
    int* blksum = ibase + 3 * N;
    int* nbr = ibase + 3 * N + 256;

    zero_kernel<<<(3072 + N + 255) / 256, 256, 0, stream>>>(stats, 3072 + N);

    int nb1 = (N + 1023) / 1024;
    hist_kernel<<<(E + 255) / 256, 256, 0, stream>>>(edst, cnt, E);
    scan1_kernel<<<nb1, 256, 0, stream>>>(cnt, ptr, blksum, N);
    scan2_kernel<<<1, 256, 0, stream>>>(blksum, nb1);
    scan3_kernel<<<(N + 255) / 256, 256, 0, stream>>>(ptr, blksum, cursor, N);
    fill_kernel<<<(E + 255) / 256, 256, 0, stream>>>(esrc, edst, cursor, nbr, E);

    int n8 = N * 8;
    int gg = (N + 63) / 64;
    to_bf16_kernel<<<(n8 + 255) / 256, 256, 0, stream>>>(x, table, n8);

    for (int i = 0; i < 3; i++) {
        float* st = stats + (size_t)(2 * i) * 512;      // inner BN sums
        float* so = stats + (size_t)(2 * i + 1) * 512;  // outer BN sums (layers 0,1)
        if (i == 0) {
            gin_gemm_kernel<false><<<gg, 256, 0, stream>>>(
                (const ushort*)table, ptr, cnt, nbr, eps_gin, i, nullptr, nullptr,
                W1 + (size_t)i * 4096, b1 + (size_t)i * 64, S1, st, N);
        } else {
            float* sp = stats + (size_t)(2 * (i - 1) + 1) * 512;
            gin_gemm_kernel<true><<<gg, 256, 0, stream>>>(
                (const ushort*)table, ptr, cnt, nbr, eps_gin, i, sp + 256, sp + 384,
                W1 + (size_t)i * 4096, b1 + (size_t)i * 64, S1, st, N);
        }
        finalize_kernel<<<1, 64, 0, stream>>>(st, g1 + (size_t)i * 64, be1 + (size_t)i * 64,
                                              st + 256, st + 384, 64, invN);
        if (i < 2) {
            // write raw-X bf16 table for next layer's gather; stats from fp32
            gemm_kernel<64, true><<<gg, 256, 0, stream>>>(S1, W2 + (size_t)i * 4096,
                                                          b2 + (size_t)i * 64, st + 256,
                                                          st + 384, nullptr, table, so, N);
            finalize_kernel<<<1, 64, 0, stream>>>(so, g_bn + (size_t)i * 64,
                                                  b_bn + (size_t)i * 64, so + 256, so + 384, 64,
                                                  invN);
        } else {
            // layer 2: fp32 X for the head, no outer BN stats
            gemm_kernel<64, false><<<gg, 256, 0, stream>>>(S1, W2 + (size_t)i * 4096,
                                                           b2 + (size_t)i * 64, st + 256,
                                                           st + 384, X, nullptr, nullptr, N);
        }
    }

    float* sf = stats + (size_t)5 * 512;
    gemm_kernel<128, false><<<gg, 256, 0, stream>>>(X, Wf1, bf1, nullptr, nullptr, HF, nullptr,
                                                    sf, N);
    finalize_kernel<<<1, 128, 0, stream>>>(sf, gf, bef, sf + 256, sf + 384, 128, invN);
    head_out_kernel<<<(N + 3) / 4, 256, 0, stream>>>(HF, sf + 256, sf + 384, Wf2, bf2, out, N);
}

// Round 7
// 717.634 us; speedup vs baseline: 1.1689x; 1.1689x over previous
//
#include <hip/hip_runtime.h>

#define LRELU(x) ((x) > 0.0f ? (x) : 0.01f * (x))
#define UAF __uint_as_float

__device__ inline uint pack_bf16_rne(float x, float y) {
    uint lo = __float_as_uint(x);
    uint hi = __float_as_uint(y);
    lo = (lo + 0x7fffu + ((lo >> 16) & 1u)) >> 16;
    hi = (hi + 0x7fffu + ((hi >> 16) & 1u)) & 0xffff0000u;
    return lo | hi;
}

__global__ void zero_kernel(float* p, int n) {
    int i = blockIdx.x * blockDim.x + threadIdx.x;
    if (i < n) p[i] = 0.0f;
}

// ---------- CSR build ----------
__global__ void hist_kernel(const int* __restrict__ dst, int* __restrict__ cnt, int E) {
    int e = blockIdx.x * blockDim.x + threadIdx.x;
    if (e < E) atomicAdd(&cnt[dst[e]], 1);
}

__global__ __launch_bounds__(256) void scan1_kernel(const int* __restrict__ cnt,
                                                    int* __restrict__ ptr,
                                                    int* __restrict__ blksum, int n) {
    __shared__ int sh[256];
    int t = threadIdx.x;
    int base = blockIdx.x * 1024 + t * 4;
    int c0 = (base + 0 < n) ? cnt[base + 0] : 0;
    int c1 = (base + 1 < n) ? cnt[base + 1] : 0;
    int c2 = (base + 2 < n) ? cnt[base + 2] : 0;
    int c3 = (base + 3 < n) ? cnt[base + 3] : 0;
    int tsum = c0 + c1 + c2 + c3;
    sh[t] = tsum;
    __syncthreads();
    for (int o = 1; o < 256; o <<= 1) {
        int v = (t >= o) ? sh[t - o] : 0;
        __syncthreads();
        sh[t] += v;
        __syncthreads();
    }
    int excl = sh[t] - tsum;
    if (base + 0 < n) ptr[base + 0] = excl;
    excl += c0;
    if (base + 1 < n) ptr[base + 1] = excl;
    excl += c1;
    if (base + 2 < n) ptr[base + 2] = excl;
    excl += c2;
    if (base + 3 < n) ptr[base + 3] = excl;
    if (t == 255) blksum[blockIdx.x] = sh[255];
}

__global__ __launch_bounds__(256) void scan2_kernel(int* __restrict__ blksum, int nb) {
    __shared__ int sh[256];
    int t = threadIdx.x;
    int v0 = (t < nb) ? blksum[t] : 0;
    sh[t] = v0;
    __syncthreads();
    for (int o = 1; o < 256; o <<= 1) {
        int v = (t >= o) ? sh[t - o] : 0;
        __syncthreads();
        sh[t] += v;
        __syncthreads();
    }
    if (t < nb) blksum[t] = sh[t] - v0;
}

__global__ void scan3_kernel(int* __restrict__ ptr, const int* __restrict__ blksum,
                             int* __restrict__ cursor, int n) {
    int i = blockIdx.x * blockDim.x + threadIdx.x;
    if (i >= n) return;
    int p = ptr[i] + blksum[i >> 10];
    ptr[i] = p;
    cursor[i] = p;
}

// nt store: avoid L2 line-bounce on random 4B writes (r5: 105MB HBM WRITE for 6.4MB array)
__global__ void fill_kernel(const int* __restrict__ src, const int* __restrict__ dst,
                            int* __restrict__ cursor, int* __restrict__ nbr, int E) {
    int e = blockIdx.x * blockDim.x + threadIdx.x;
    if (e >= E) return;
    int d = dst[e];
    int pos = atomicAdd(&cursor[d], 1);
    __builtin_nontemporal_store(src[e], &nbr[pos]);
}

// ---------- fp32 -> bf16 (RNE) feature table (layer 0 input only) ----------
__global__ __launch_bounds__(256) void to_bf16_kernel(const float* __restrict__ in,
                                                      uint* __restrict__ table, int n8) {
    int i = blockIdx.x * blockDim.x + threadIdx.x;
    if (i >= n8) return;
    float4 a = *(const float4*)&in[(size_t)i * 8];
    float4 b = *(const float4*)&in[(size_t)i * 8 + 4];
    uint4 p = make_uint4(pack_bf16_rne(a.x, a.y), pack_bf16_rne(a.z, a.w),
                         pack_bf16_rne(b.x, b.y), pack_bf16_rne(b.z, b.w));
    *(uint4*)&table[(size_t)i * 4] = p;
}

// ---------- aggregation: one 64-lane wave per node (max concurrency; r6 lesson:
// fused version collapsed MLP 8x and regressed). Half-waves split the neighbor list,
// lane sl owns features (2sl,2sl+1) via one uint; 4 independent loads in flight per
// half (8/wave); BN-affine+LeakyReLU on raw bf16 table values for ACT layers. ----------
template <bool ACT>
__global__ __launch_bounds__(256) void gather_kernel(
    const ushort* __restrict__ table, const int* __restrict__ ptr,
    const int* __restrict__ cnt, const int* __restrict__ nbr,
    const float* __restrict__ eps_gin, int layer, const float* __restrict__ scale,
    const float* __restrict__ shift, float* __restrict__ agg, int N) {
    int gtid = blockIdx.x * blockDim.x + threadIdx.x;
    int node = gtid >> 6;
    if (node >= N) return;
    int lane = threadIdx.x & 63;
    int half = lane >> 5;
    int sl = lane & 31;
    float sc0 = 1.0f, sh0 = 0.0f, sc1 = 1.0f, sh1 = 0.0f;
    if (ACT) {
        sc0 = scale[2 * sl + 0];
        sh0 = shift[2 * sl + 0];
        sc1 = scale[2 * sl + 1];
        sh1 = shift[2 * sl + 1];
    }
    int start = ptr[node];
    int deg = cnt[node];
    float a0 = 0.0f, a1 = 0.0f;
    int j = half;
    for (; j + 6 < deg; j += 8) {  // 4 independent row loads per half
        int nA = nbr[start + j + 0];
        int nB = nbr[start + j + 2];
        int nC = nbr[start + j + 4];
        int nD = nbr[start + j + 6];
        uint vA = *(const uint*)(table + (size_t)nA * 64 + sl * 2);
        uint vB = *(const uint*)(table + (size_t)nB * 64 + sl * 2);
        uint vC = *(const uint*)(table + (size_t)nC * 64 + sl * 2);
        uint vD = *(const uint*)(table + (size_t)nD * 64 + sl * 2);
        float fA0 = UAF(vA << 16), fA1 = UAF(vA & 0xffff0000u);
        float fB0 = UAF(vB << 16), fB1 = UAF(vB & 0xffff0000u);
        float fC0 = UAF(vC << 16), fC1 = UAF(vC & 0xffff0000u);
        float fD0 = UAF(vD << 16), fD1 = UAF(vD & 0xffff0000u);
        if (ACT) {
            fA0 = LRELU(fA0 * sc0 + sh0);
            fA1 = LRELU(fA1 * sc1 + sh1);
            fB0 = LRELU(fB0 * sc0 + sh0);
            fB1 = LRELU(fB1 * sc1 + sh1);
            fC0 = LRELU(fC0 * sc0 + sh0);
            fC1 = LRELU(fC1 * sc1 + sh1);
            fD0 = LRELU(fD0 * sc0 + sh0);
            fD1 = LRELU(fD1 * sc1 + sh1);
        }
        a0 += (fA0 + fB0) + (fC0 + fD0);
        a1 += (fA1 + fB1) + (fC1 + fD1);
    }
    for (; j < deg; j += 2) {
        int nA = nbr[start + j];
        uint vA = *(const uint*)(table + (size_t)nA * 64 + sl * 2);
        float fA0 = UAF(vA << 16), fA1 = UAF(vA & 0xffff0000u);
        if (ACT) {
            fA0 = LRELU(fA0 * sc0 + sh0);
            fA1 = LRELU(fA1 * sc1 + sh1);
        }
        a0 += fA0;
        a1 += fA1;
    }
    a0 += __shfl(a0, lane ^ 32);
    a1 += __shfl(a1, lane ^ 32);
    uint vs = *(const uint*)(table + (size_t)node * 64 + sl * 2);
    float s0 = UAF(vs << 16), s1 = UAF(vs & 0xffff0000u);
    if (ACT) {
        s0 = LRELU(s0 * sc0 + sh0);
        s1 = LRELU(s1 * sc1 + sh1);
    }
    float ep = 1.0f + eps_gin[layer];
    a0 += ep * s0;
    a1 += ep * s1;
    if (half == 0) *(float2*)&agg[(size_t)node * 64 + sl * 2] = make_float2(a0, a1);
}

__global__ void finalize_kernel(const float* __restrict__ sums, const float* __restrict__ g,
                                const float* __restrict__ be, float* __restrict__ scale,
                                float* __restrict__ shift, int C, float invN) {
    int d = threadIdx.x;
    if (d >= C) return;
    float mean = sums[d] * invN;
    float var = sums[C + d] * invN - mean * mean;
    float sc = g[d] * rsqrtf(var + 1e-5f);
    scale[d] = sc;
    shift[d] = be[d] - mean * sc;
}

// out = act(in) @ W + bias; OUTBF16: write RNE-packed bf16 table (stats from fp32)
template <int COLS, bool OUTBF16>
__global__ __launch_bounds__(256, 4) void gemm_kernel(const float* __restrict__ in,
                                                      const float* __restrict__ W,
                                                      const float* __restrict__ bias,
                                                      const float* __restrict__ scale,
                                                      const float* __restrict__ shift,
                                                      float* __restrict__ out,
                                                      uint* __restrict__ tout,
                                                      float* __restrict__ sums, int nrows) {
    __shared__ float inT[64][68];
    __shared__ float ws[64][COLS];
    int t = threadIdx.x;
    int row0 = blockIdx.x * 64;

    for (int i = 0; i < 4; i++) {
        int f = t + 256 * i;
        int r = f >> 4;
        int ch = f & 15;
        int gr = row0 + r;
        float4 v = make_float4(0.f, 0.f, 0.f, 0.f);
        if (gr < nrows) v = *(const float4*)&in[(size_t)gr * 64 + ch * 4];
        if (scale) {
            int d = ch * 4;
            v.x = LRELU(v.x * scale[d + 0] + shift[d + 0]);
            v.y = LRELU(v.y * scale[d + 1] + shift[d + 1]);
            v.z = LRELU(v.z * scale[d + 2] + shift[d + 2]);
            v.w = LRELU(v.w * scale[d + 3] + shift[d + 3]);
        }
        inT[ch * 4 + 0][r] = v.x;
        inT[ch * 4 + 1][r] = v.y;
        inT[ch * 4 + 2][r] = v.z;
        inT[ch * 4 + 3][r] = v.w;
    }
    for (int i = 0; i < COLS / 16; i++) {
        int f = t + 256 * i;
        int k = f / (COLS / 4);
        int c4 = f % (COLS / 4);
        *(float4*)&ws[k][c4 * 4] = *(const float4*)&W[(size_t)k * COLS + c4 * 4];
    }
    __syncthreads();

    constexpr int NCH = COLS / 64;
    int rg = t >> 4;
    int cg = t & 15;
    int r0 = rg * 4;
    int c0 = cg * 4;
    float acc[4][NCH * 4];
#pragma unroll
    for (int r = 0; r < 4; r++)
#pragma unroll
        for (int c = 0; c < NCH * 4; c++) acc[r][c] = 0.0f;

#pragma unroll 16
    for (int k = 0; k < 64; k++) {
        float4 a = *(const float4*)&inT[k][r0];
        float ar[4] = {a.x, a.y, a.z, a.w};
#pragma unroll
        for (int jj = 0; jj < NCH; jj++) {
            float4 w4 = *(const float4*)&ws[k][c0 + jj * 64];
            float wr[4] = {w4.x, w4.y, w4.z, w4.w};
#pragma unroll
            for (int r = 0; r < 4; r++)
#pragma unroll
                for (int c = 0; c < 4; c++) acc[r][jj * 4 + c] += ar[r] * wr[c];
        }
    }

    float ps[NCH * 4], ps2[NCH * 4];
#pragma unroll
    for (int c = 0; c < NCH * 4; c++) ps[c] = ps2[c] = 0.0f;
#pragma unroll
    for (int r = 0; r < 4; r++) {
        int gr = row0 + r0 + r;
        if (gr < nrows) {
#pragma unroll
            for (int jj = 0; jj < NCH; jj++) {
                float4 bv = *(const float4*)&bias[c0 + jj * 64];
                float4 o = make_float4(acc[r][jj * 4 + 0] + bv.x, acc[r][jj * 4 + 1] + bv.y,
                                       acc[r][jj * 4 + 2] + bv.z, acc[r][jj * 4 + 3] + bv.w);
                if (OUTBF16) {
                    uint2 pk = make_uint2(pack_bf16_rne(o.x, o.y), pack_bf16_rne(o.z, o.w));
                    *(uint2*)&tout[(size_t)gr * 32 + (c0 >> 1)] = pk;
                } else {
                    *(float4*)&out[(size_t)gr * COLS + c0 + jj * 64] = o;
                }
                ps[jj * 4 + 0] += o.x;
                ps2[jj * 4 + 0] += o.x * o.x;
                ps[jj * 4 + 1] += o.y;
                ps2[jj * 4 + 1] += o.y * o.y;
                ps[jj * 4 + 2] += o.z;
                ps2[jj * 4 + 2] += o.z * o.z;
                ps[jj * 4 + 3] += o.w;
                ps2[jj * 4 + 3] += o.w * o.w;
            }
        }
    }

    if (sums == nullptr) return;

    __syncthreads();
    float* red = &inT[0][0];
    float* red2 = red + 16 * COLS;
#pragma unroll
    for (int jj = 0; jj < NCH; jj++) {
        *(float4*)&red[rg * COLS + c0 + jj * 64] = *(float4*)&ps[jj * 4];
        *(float4*)&red2[rg * COLS + c0 + jj * 64] = *(float4*)&ps2[jj * 4];
    }
    __syncthreads();
    if (t < COLS) {
        float s = 0.0f, s2 = 0.0f;
#pragma unroll
        for (int j = 0; j < 16; j++) {
            s += red[j * COLS + t];
            s2 += red2[j * COLS + t];
        }
        atomicAdd(&sums[t], s);
        atomicAdd(&sums[COLS + t], s2);
    }
}

__global__ void head_out_kernel(const float* __restrict__ hf, const float* __restrict__ scale,
                                const float* __restrict__ shift, const float* __restrict__ Wf2,
                                const float* __restrict__ bf2, float* __restrict__ out,
                                int nrows) {
    int gtid = blockIdx.x * blockDim.x + threadIdx.x;
    int wid = gtid >> 6;
    int l = threadIdx.x & 63;
    if (wid >= nrows) return;
    float v0 = hf[(size_t)wid * 128 + l];
    float v1 = hf[(size_t)wid * 128 + 64 + l];
    v0 = LRELU(v0 * scale[l] + shift[l]);
    v1 = LRELU(v1 * scale[64 + l] + shift[64 + l]);
    float p = v0 * Wf2[l] + v1 * Wf2[64 + l];
    for (int o = 32; o > 0; o >>= 1) p += __shfl_down(p, o);
    if (l == 0) out[wid] = p + bf2[0];
}

extern "C" void kernel_launch(void* const* d_in, const int* in_sizes, int n_in, void* d_out,
                              int out_size, void* d_ws, size_t ws_size, hipStream_t stream) {
    const float* x = (const float*)d_in[0];
    const int* esrc = (const int*)d_in[1];
    const int* edst = (const int*)d_in[2];
    const float* W1 = (const float*)d_in[3];
    const float* b1 = (const float*)d_in[4];
    const float* g1 = (const float*)d_in[5];
    const float* be1 = (const float*)d_in[6];
    const float* W2 = (const float*)d_in[7];
    const float* b2 = (const float*)d_in[8];
    const float* eps_gin = (const float*)d_in[9];
    const float* g_bn = (const float*)d_in[10];
    const float* b_bn = (const float*)d_in[11];
    const float* Wf1 = (const float*)d_in[12];
    const float* bf1 = (const float*)d_in[13];
    const float* gf = (const float*)d_in[14];
    const float* bef = (const float*)d_in[15];
    const float* Wf2 = (const float*)d_in[16];
    const float* bf2 = (const float*)d_in[17];
    float* out = (float*)d_out;

    int N = in_sizes[0] / 64;
    int E = in_sizes[1];
    float invN = 1.0f / (float)N;

    float* ws = (float*)d_ws;
    size_t ND = (size_t)N * 64;
    // region A: bf16 table (ND/2 floats) through layer-2 gather; then fp32 X (layer-2 out)
    float* A = ws;
    uint* table = (uint*)A;
    float* X = A;
    float* S1 = ws + ND;      // h1; later HF low half
    float* S2 = ws + 2 * ND;  // agg; later HF high half
    float* HF = S1;           // N x 128 spans S1+S2
    float* stats = ws + 3 * ND;
    int* ibase = (int*)(stats + 3072);
    int* cnt = ibase;
    int* ptr = ibase + N;
    int* cursor = ibase + 2 * N;
    int* blksum = ibase + 3 * N;
    int* nbr = ibase + 3 * N + 256;

    zero_kernel<<<(3072 + N + 255) / 256, 256, 0, stream>>>(stats, 3072 + N);

    int nb1 = (N + 1023) / 1024;
    hist_kernel<<<(E + 255) / 256, 256, 0, stream>>>(edst, cnt, E);
    scan1_kernel<<<nb1, 256, 0, stream>>>(cnt, ptr, blksum, N);
    scan2_kernel<<<1, 256, 0, stream>>>(blksum, nb1);
    scan3_kernel<<<(N + 255) / 256, 256, 0, stream>>>(ptr, blksum, cursor, N);
    fill_kernel<<<(E + 255) / 256, 256, 0, stream>>>(esrc, edst, cursor, nbr, E);

    int n8 = N * 8;
    int gg = (N + 63) / 64;
    int gblocks = (N * 64 + 255) / 256;
    to_bf16_kernel<<<(n8 + 255) / 256, 256, 0, stream>>>(x, table, n8);

    for (int i = 0; i < 3; i++) {
        float* st = stats + (size_t)(2 * i) * 512;      // inner BN sums
        float* so = stats + (size_t)(2 * i + 1) * 512;  // outer BN sums (layers 0,1)
        if (i == 0) {
            gather_kernel<false><<<gblocks, 256, 0, stream>>>(
                (const ushort*)table, ptr, cnt, nbr, eps_gin, i, nullptr, nullptr, S2, N);
        } else {
            float* sp = stats + (size_t)(2 * (i - 1) + 1) * 512;
            gather_kernel<true><<<gblocks, 256, 0, stream>>>(
                (const ushort*)table, ptr, cnt, nbr, eps_gin, i, sp + 256, sp + 384, S2, N);
        }
        gemm_kernel<64, false><<<gg, 256, 0, stream>>>(S2, W1 + (size_t)i * 4096,
                                                       b1 + (size_t)i * 64, nullptr, nullptr, S1,
                                                       nullptr, st, N);
        finalize_kernel<<<1, 64, 0, stream>>>(st, g1 + (size_t)i * 64, be1 + (size_t)i * 64,
                                              st + 256, st + 384, 64, invN);
        if (i < 2) {
            // write raw-X bf16 table for next layer's gather; stats from fp32
            gemm_kernel<64, true><<<gg, 256, 0, stream>>>(S1, W2 + (size_t)i * 4096,
                                                          b2 + (size_t)i * 64, st + 256,
                                                          st + 384, nullptr, table, so, N);
            finalize_kernel<<<1, 64, 0, stream>>>(so, g_bn + (size_t)i * 64,
                                                  b_bn + (size_t)i * 64, so + 256, so + 384, 64,
                                                  invN);
        } else {
            // layer 2: fp32 X for the head (overwrites dead table), no outer BN stats
            gemm_kernel<64, false><<<gg, 256, 0, stream>>>(S1, W2 + (size_t)i * 4096,
                                                           b2 + (size_t)i * 64, st + 256,
                                                           st + 384, X, nullptr, nullptr, N);
        }
    }

    float* sf = stats + (size_t)5 * 512;
    gemm_kernel<128, false><<<gg, 256, 0, stream>>>(X, Wf1, bf1, nullptr, nullptr, HF, nullptr,
                                                    sf, N);
    finalize_kernel<<<1, 128, 0, stream>>>(sf, gf, bef, sf + 256, sf + 384, 128, invN);
    head_out_kernel<<<(N + 3) / 4, 256, 0, stream>>>(HF, sf + 256, sf + 384, Wf2, bf2, out, N);
}

// Round 8
// 572.758 us; speedup vs baseline: 1.4646x; 1.2529x over previous
//
#include <hip/hip_runtime.h>

#define LRELU(x) ((x) > 0.0f ? (x) : 0.01f * (x))
#define UAF __uint_as_float

__device__ inline uint pack_bf16_rne(float x, float y) {
    uint lo = __float_as_uint(x);
    uint hi = __float_as_uint(y);
    lo = (lo + 0x7fffu + ((lo >> 16) & 1u)) >> 16;
    hi = (hi + 0x7fffu + ((hi >> 16) & 1u)) & 0xffff0000u;
    return lo | hi;
}

__global__ void zero_kernel(float* p, int n) {
    int i = blockIdx.x * blockDim.x + threadIdx.x;
    if (i < n) p[i] = 0.0f;
}

// ---------- bucketed CSR build (r8): buckets of 256 dst nodes ----------
// K1: per-block LDS hist -> global bucket counts (replaces 1.6M global atomics w/ 77k)
__global__ __launch_bounds__(256) void bhist_kernel(const int* __restrict__ dst,
                                                    int* __restrict__ bcnt, int E, int NB) {
    __shared__ int h[512];
    for (int i = threadIdx.x; i < NB; i += 256) h[i] = 0;
    __syncthreads();
    int base = blockIdx.x * 8192;
    int end = min(E, base + 8192);
    for (int e = base + threadIdx.x; e < end; e += 256) atomicAdd(&h[dst[e] >> 8], 1);
    __syncthreads();
    for (int i = threadIdx.x; i < NB; i += 256)
        if (h[i]) atomicAdd(&bcnt[i], h[i]);
}

// K2: single-block scan of bucket counts (NB <= 512)
__global__ __launch_bounds__(512) void bscan_kernel(const int* __restrict__ bcnt,
                                                    int* __restrict__ boff,
                                                    int* __restrict__ bcur, int NB) {
    __shared__ int sh[512];
    int t = threadIdx.x;
    int v = (t < NB) ? bcnt[t] : 0;
    sh[t] = v;
    __syncthreads();
    for (int o = 1; o < 512; o <<= 1) {
        int u = (t >= o) ? sh[t - o] : 0;
        __syncthreads();
        sh[t] += u;
        __syncthreads();
    }
    if (t < NB) {
        boff[t] = sh[t] - v;
        bcur[t] = sh[t] - v;
    }
}

// K3: scatter edges into bucket-contiguous packed pairs (src<<8 | local_dst)
__global__ __launch_bounds__(256) void bscatter_kernel(const int* __restrict__ src,
                                                       const int* __restrict__ dst,
                                                       int* __restrict__ bcur,
                                                       uint* __restrict__ pairs, int E, int NB) {
    __shared__ int h[512];
    __shared__ int bbase[512];
    for (int i = threadIdx.x; i < NB; i += 256) h[i] = 0;
    __syncthreads();
    int base = blockIdx.x * 8192;
    int end = min(E, base + 8192);
    for (int e = base + threadIdx.x; e < end; e += 256) atomicAdd(&h[dst[e] >> 8], 1);
    __syncthreads();
    for (int i = threadIdx.x; i < NB; i += 256) {
        bbase[i] = h[i] ? atomicAdd(&bcur[i], h[i]) : 0;
        h[i] = 0;
    }
    __syncthreads();
    for (int e = base + threadIdx.x; e < end; e += 256) {
        int d = dst[e];
        int b = d >> 8;
        int o = atomicAdd(&h[b], 1);
        pairs[bbase[b] + o] = ((uint)src[e] << 8) | (uint)(d & 255);
    }
}

// K4: one block per bucket: local hist+scan -> ptr/cnt, then scatter nbr within the
// bucket's private window (single-XCD writes merge in L2 -> coalesced writeback)
__global__ __launch_bounds__(256) void bcsr_kernel(const uint* __restrict__ pairs,
                                                   const int* __restrict__ boff,
                                                   int* __restrict__ ptr, int* __restrict__ cnt,
                                                   int* __restrict__ nbr, int N, int NB, int E) {
    __shared__ int h[256];
    __shared__ int sc[256];
    int b = blockIdx.x;
    int lo = boff[b];
    int hi = (b + 1 < NB) ? boff[b + 1] : E;
    int t = threadIdx.x;
    h[t] = 0;
    __syncthreads();
    for (int i = lo + t; i < hi; i += 256) atomicAdd(&h[pairs[i] & 255u], 1);
    __syncthreads();
    int v = h[t];
    sc[t] = v;
    __syncthreads();
    for (int o = 1; o < 256; o <<= 1) {
        int u = (t >= o) ? sc[t - o] : 0;
        __syncthreads();
        sc[t] += u;
        __syncthreads();
    }
    int excl = sc[t] - v;
    int node = (b << 8) + t;
    if (node < N) {
        ptr[node] = lo + excl;
        cnt[node] = v;
    }
    __syncthreads();
    h[t] = excl;  // local cursor
    __syncthreads();
    for (int i = lo + t; i < hi; i += 256) {
        uint p = pairs[i];
        int ld = p & 255u;
        int o = atomicAdd(&h[ld], 1);
        nbr[lo + o] = (int)(p >> 8);
    }
}

// ---------- fp32 -> bf16 (RNE) feature table (layer 0 input only) ----------
__global__ __launch_bounds__(256) void to_bf16_kernel(const float* __restrict__ in,
                                                      uint* __restrict__ table, int n8) {
    int i = blockIdx.x * blockDim.x + threadIdx.x;
    if (i >= n8) return;
    float4 a = *(const float4*)&in[(size_t)i * 8];
    float4 b = *(const float4*)&in[(size_t)i * 8 + 4];
    uint4 p = make_uint4(pack_bf16_rne(a.x, a.y), pack_bf16_rne(a.z, a.w),
                         pack_bf16_rne(b.x, b.y), pack_bf16_rne(b.z, b.w));
    *(uint4*)&table[(size_t)i * 4] = p;
}

// ---------- aggregation: one 64-lane wave per node (max concurrency; r6 lesson:
// fusing into gemm collapsed MLP 8x and regressed). Half-waves split the neighbor
// list; lane sl owns features (2sl,2sl+1); 4 independent loads in flight per half. ----------
template <bool ACT>
__global__ __launch_bounds__(256) void gather_kernel(
    const ushort* __restrict__ table, const int* __restrict__ ptr,
    const int* __restrict__ cnt, const int* __restrict__ nbr,
    const float* __restrict__ eps_gin, int layer, const float* __restrict__ scale,
    const float* __restrict__ shift, float* __restrict__ agg, int N) {
    int gtid = blockIdx.x * blockDim.x + threadIdx.x;
    int node = gtid >> 6;
    if (node >= N) return;
    int lane = threadIdx.x & 63;
    int half = lane >> 5;
    int sl = lane & 31;
    float sc0 = 1.0f, sh0 = 0.0f, sc1 = 1.0f, sh1 = 0.0f;
    if (ACT) {
        sc0 = scale[2 * sl + 0];
        sh0 = shift[2 * sl + 0];
        sc1 = scale[2 * sl + 1];
        sh1 = shift[2 * sl + 1];
    }
    int start = ptr[node];
    int deg = cnt[node];
    float a0 = 0.0f, a1 = 0.0f;
    int j = half;
    for (; j + 6 < deg; j += 8) {
        int nA = nbr[start + j + 0];
        int nB = nbr[start + j + 2];
        int nC = nbr[start + j + 4];
        int nD = nbr[start + j + 6];
        uint vA = *(const uint*)(table + (size_t)nA * 64 + sl * 2);
        uint vB = *(const uint*)(table + (size_t)nB * 64 + sl * 2);
        uint vC = *(const uint*)(table + (size_t)nC * 64 + sl * 2);
        uint vD = *(const uint*)(table + (size_t)nD * 64 + sl * 2);
        float fA0 = UAF(vA << 16), fA1 = UAF(vA & 0xffff0000u);
        float fB0 = UAF(vB << 16), fB1 = UAF(vB & 0xffff0000u);
        float fC0 = UAF(vC << 16), fC1 = UAF(vC & 0xffff0000u);
        float fD0 = UAF(vD << 16), fD1 = UAF(vD & 0xffff0000u);
        if (ACT) {
            fA0 = LRELU(fA0 * sc0 + sh0);
            fA1 = LRELU(fA1 * sc1 + sh1);
            fB0 = LRELU(fB0 * sc0 + sh0);
            fB1 = LRELU(fB1 * sc1 + sh1);
            fC0 = LRELU(fC0 * sc0 + sh0);
            fC1 = LRELU(fC1 * sc1 + sh1);
            fD0 = LRELU(fD0 * sc0 + sh0);
            fD1 = LRELU(fD1 * sc1 + sh1);
        }
        a0 += (fA0 + fB0) + (fC0 + fD0);
        a1 += (fA1 + fB1) + (fC1 + fD1);
    }
    for (; j < deg; j += 2) {
        int nA = nbr[start + j];
        uint vA = *(const uint*)(table + (size_t)nA * 64 + sl * 2);
        float fA0 = UAF(vA << 16), fA1 = UAF(vA & 0xffff0000u);
        if (ACT) {
            fA0 = LRELU(fA0 * sc0 + sh0);
            fA1 = LRELU(fA1 * sc1 + sh1);
        }
        a0 += fA0;
        a1 += fA1;
    }
    a0 += __shfl(a0, lane ^ 32);
    a1 += __shfl(a1, lane ^ 32);
    uint vs = *(const uint*)(table + (size_t)node * 64 + sl * 2);
    float s0 = UAF(vs << 16), s1 = UAF(vs & 0xffff0000u);
    if (ACT) {
        s0 = LRELU(s0 * sc0 + sh0);
        s1 = LRELU(s1 * sc1 + sh1);
    }
    float ep = 1.0f + eps_gin[layer];
    a0 += ep * s0;
    a1 += ep * s1;
    if (half == 0) *(float2*)&agg[(size_t)node * 64 + sl * 2] = make_float2(a0, a1);
}

__global__ void finalize_kernel(const float* __restrict__ sums, const float* __restrict__ g,
                                const float* __restrict__ be, float* __restrict__ scale,
                                float* __restrict__ shift, int C, float invN) {
    int d = threadIdx.x;
    if (d >= C) return;
    float mean = sums[d] * invN;
    float var = sums[C + d] * invN - mean * mean;
    float sc = g[d] * rsqrtf(var + 1e-5f);
    scale[d] = sc;
    shift[d] = be[d] - mean * sc;
}

// out = act(in) @ W + bias; OUTBF16: write RNE-packed bf16 table (stats from fp32)
template <int COLS, bool OUTBF16>
__global__ __launch_bounds__(256, 4) void gemm_kernel(const float* __restrict__ in,
                                                      const float* __restrict__ W,
                                                      const float* __restrict__ bias,
                                                      const float* __restrict__ scale,
                                                      const float* __restrict__ shift,
                                                      float* __restrict__ out,
                                                      uint* __restrict__ tout,
                                                      float* __restrict__ sums, int nrows) {
    __shared__ float inT[64][68];
    __shared__ float ws[64][COLS];
    int t = threadIdx.x;
    int row0 = blockIdx.x * 64;

    for (int i = 0; i < 4; i++) {
        int f = t + 256 * i;
        int r = f >> 4;
        int ch = f & 15;
        int gr = row0 + r;
        float4 v = make_float4(0.f, 0.f, 0.f, 0.f);
        if (gr < nrows) v = *(const float4*)&in[(size_t)gr * 64 + ch * 4];
        if (scale) {
            int d = ch * 4;
            v.x = LRELU(v.x * scale[d + 0] + shift[d + 0]);
            v.y = LRELU(v.y * scale[d + 1] + shift[d + 1]);
            v.z = LRELU(v.z * scale[d + 2] + shift[d + 2]);
            v.w = LRELU(v.w * scale[d + 3] + shift[d + 3]);
        }
        inT[ch * 4 + 0][r] = v.x;
        inT[ch * 4 + 1][r] = v.y;
        inT[ch * 4 + 2][r] = v.z;
        inT[ch * 4 + 3][r] = v.w;
    }
    for (int i = 0; i < COLS / 16; i++) {
        int f = t + 256 * i;
        int k = f / (COLS / 4);
        int c4 = f % (COLS / 4);
        *(float4*)&ws[k][c4 * 4] = *(const float4*)&W[(size_t)k * COLS + c4 * 4];
    }
    __syncthreads();

    constexpr int NCH = COLS / 64;
    int rg = t >> 4;
    int cg = t & 15;
    int r0 = rg * 4;
    int c0 = cg * 4;
    float acc[4][NCH * 4];
#pragma unroll
    for (int r = 0; r < 4; r++)
#pragma unroll
        for (int c = 0; c < NCH * 4; c++) acc[r][c] = 0.0f;

#pragma unroll 16
    for (int k = 0; k < 64; k++) {
        float4 a = *(const float4*)&inT[k][r0];
        float ar[4] = {a.x, a.y, a.z, a.w};
#pragma unroll
        for (int jj = 0; jj < NCH; jj++) {
            float4 w4 = *(const float4*)&ws[k][c0 + jj * 64];
            float wr[4] = {w4.x, w4.y, w4.z, w4.w};
#pragma unroll
            for (int r = 0; r < 4; r++)
#pragma unroll
                for (int c = 0; c < 4; c++) acc[r][jj * 4 + c] += ar[r] * wr[c];
        }
    }

    float ps[NCH * 4], ps2[NCH * 4];
#pragma unroll
    for (int c = 0; c < NCH * 4; c++) ps[c] = ps2[c] = 0.0f;
#pragma unroll
    for (int r = 0; r < 4; r++) {
        int gr = row0 + r0 + r;
        if (gr < nrows) {
#pragma unroll
            for (int jj = 0; jj < NCH; jj++) {
                float4 bv = *(const float4*)&bias[c0 + jj * 64];
                float4 o = make_float4(acc[r][jj * 4 + 0] + bv.x, acc[r][jj * 4 + 1] + bv.y,
                                       acc[r][jj * 4 + 2] + bv.z, acc[r][jj * 4 + 3] + bv.w);
                if (OUTBF16) {
                    uint2 pk = make_uint2(pack_bf16_rne(o.x, o.y), pack_bf16_rne(o.z, o.w));
                    *(uint2*)&tout[(size_t)gr * 32 + (c0 >> 1)] = pk;
                } else {
                    *(float4*)&out[(size_t)gr * COLS + c0 + jj * 64] = o;
                }
                ps[jj * 4 + 0] += o.x;
                ps2[jj * 4 + 0] += o.x * o.x;
                ps[jj * 4 + 1] += o.y;
                ps2[jj * 4 + 1] += o.y * o.y;
                ps[jj * 4 + 2] += o.z;
                ps2[jj * 4 + 2] += o.z * o.z;
                ps[jj * 4 + 3] += o.w;
                ps2[jj * 4 + 3] += o.w * o.w;
            }
        }
    }

    if (sums == nullptr) return;

    __syncthreads();
    float* red = &inT[0][0];
    float* red2 = red + 16 * COLS;
#pragma unroll
    for (int jj = 0; jj < NCH; jj++) {
        *(float4*)&red[rg * COLS + c0 + jj * 64] = *(float4*)&ps[jj * 4];
        *(float4*)&red2[rg * COLS + c0 + jj * 64] = *(float4*)&ps2[jj * 4];
    }
    __syncthreads();
    if (t < COLS) {
        float s = 0.0f, s2 = 0.0f;
#pragma unroll
        for (int j = 0; j < 16; j++) {
            s += red[j * COLS + t];
            s2 += red2[j * COLS + t];
        }
        atomicAdd(&sums[t], s);
        atomicAdd(&sums[COLS + t], s2);
    }
}

__global__ void head_out_kernel(const float* __restrict__ hf, const float* __restrict__ scale,
                                const float* __restrict__ shift, const float* __restrict__ Wf2,
                                const float* __restrict__ bf2, float* __restrict__ out,
                                int nrows) {
    int gtid = blockIdx.x * blockDim.x + threadIdx.x;
    int wid = gtid >> 6;
    int l = threadIdx.x & 63;
    if (wid >= nrows) return;
    float v0 = hf[(size_t)wid * 128 + l];
    float v1 = hf[(size_t)wid * 128 + 64 + l];
    v0 = LRELU(v0 * scale[l] + shift[l]);
    v1 = LRELU(v1 * scale[64 + l] + shift[64 + l]);
    float p = v0 * Wf2[l] + v1 * Wf2[64 + l];
    for (int o = 32; o > 0; o >>= 1) p += __shfl_down(p, o);
    if (l == 0) out[wid] = p + bf2[0];
}

extern "C" void kernel_launch(void* const* d_in, const int* in_sizes, int n_in, void* d_out,
                              int out_size, void* d_ws, size_t ws_size, hipStream_t stream) {
    const float* x = (const float*)d_in[0];
    const int* esrc = (const int*)d_in[1];
    const int* edst = (const int*)d_in[2];
    const float* W1 = (const float*)d_in[3];
    const float* b1 = (const float*)d_in[4];
    const float* g1 = (const float*)d_in[5];
    const float* be1 = (const float*)d_in[6];
    const float* W2 = (const float*)d_in[7];
    const float* b2 = (const float*)d_in[8];
    const float* eps_gin = (const float*)d_in[9];
    const float* g_bn = (const float*)d_in[10];
    const float* b_bn = (const float*)d_in[11];
    const float* Wf1 = (const float*)d_in[12];
    const float* bf1 = (const float*)d_in[13];
    const float* gf = (const float*)d_in[14];
    const float* bef = (const float*)d_in[15];
    const float* Wf2 = (const float*)d_in[16];
    const float* bf2 = (const float*)d_in[17];
    float* out = (float*)d_out;

    int N = in_sizes[0] / 64;
    int E = in_sizes[1];
    int NB = (N + 255) / 256;  // dst buckets of 256 nodes (<=512 for N<=131072)
    float invN = 1.0f / (float)N;

    float* ws = (float*)d_ws;
    size_t ND = (size_t)N * 64;
    // region A: bf16 table (lower ND/2 floats) through layer-2 gather; pairs scratch
    // in upper half during CSR build (dead before to_bf16); fp32 X (layer-2 out) last.
    float* A = ws;
    uint* table = (uint*)A;
    float* X = A;
    uint* pairs = (uint*)(ws + ND / 2);  // E uints, fits in A upper half
    float* S1 = ws + ND;                 // h1; later HF low half
    float* S2 = ws + 2 * ND;             // agg; later HF high half
    float* HF = S1;                      // N x 128 spans S1+S2
    float* stats = ws + 3 * ND;
    int* ibase = (int*)(stats + 3072);
    int* bcnt = ibase;          // 512
    int* bcur = ibase + 512;    // 512
    int* boff = ibase + 1024;   // 512
    int* cnt = ibase + 1536;    // N
    int* ptr = cnt + N;         // N
    int* nbr = ptr + N;         // E

    // zero stats (3072 floats) + bcnt (512 ints, contiguous)
    zero_kernel<<<(3584 + 255) / 256, 256, 0, stream>>>(stats, 3584);

    int eb = (E + 8191) / 8192;
    bhist_kernel<<<eb, 256, 0, stream>>>(edst, bcnt, E, NB);
    bscan_kernel<<<1, 512, 0, stream>>>(bcnt, boff, bcur, NB);
    bscatter_kernel<<<eb, 256, 0, stream>>>(esrc, edst, bcur, pairs, E, NB);
    bcsr_kernel<<<NB, 256, 0, stream>>>(pairs, boff, ptr, cnt, nbr, N, NB, E);

    int n8 = N * 8;
    int gg = (N + 63) / 64;
    int gblocks = (N * 64 + 255) / 256;
    to_bf16_kernel<<<(n8 + 255) / 256, 256, 0, stream>>>(x, table, n8);

    for (int i = 0; i < 3; i++) {
        float* st = stats + (size_t)(2 * i) * 512;      // inner BN sums
        float* so = stats + (size_t)(2 * i + 1) * 512;  // outer BN sums (layers 0,1)
        if (i == 0) {
            gather_kernel<false><<<gblocks, 256, 0, stream>>>(
                (const ushort*)table, ptr, cnt, nbr, eps_gin, i, nullptr, nullptr, S2, N);
        } else {
            float* sp = stats + (size_t)(2 * (i - 1) + 1) * 512;
            gather_kernel<true><<<gblocks, 256, 0, stream>>>(
                (const ushort*)table, ptr, cnt, nbr, eps_gin, i, sp + 256, sp + 384, S2, N);
        }
        gemm_kernel<64, false><<<gg, 256, 0, stream>>>(S2, W1 + (size_t)i * 4096,
                                                       b1 + (size_t)i * 64, nullptr, nullptr, S1,
                                                       nullptr, st, N);
        finalize_kernel<<<1, 64, 0, stream>>>(st, g1 + (size_t)i * 64, be1 + (size_t)i * 64,
                                              st + 256, st + 384, 64, invN);
        if (i < 2) {
            gemm_kernel<64, true><<<gg, 256, 0, stream>>>(S1, W2 + (size_t)i * 4096,
                                                          b2 + (size_t)i * 64, st + 256,
                                                          st + 384, nullptr, table, so, N);
            finalize_kernel<<<1, 64, 0, stream>>>(so, g_bn + (size_t)i * 64,
                                                  b_bn + (size_t)i * 64, so + 256, so + 384, 64,
                                                  invN);
        } else {
            gemm_kernel<64, false><<<gg, 256, 0, stream>>>(S1, W2 + (size_t)i * 4096,
                                                           b2 + (size_t)i * 64, st + 256,
                                                           st + 384, X, nullptr, nullptr, N);
        }
    }

    float* sf = stats + (size_t)5 * 512;
    gemm_kernel<128, false><<<gg, 256, 0, stream>>>(X, Wf1, bf1, nullptr, nullptr, HF, nullptr,
                                                    sf, N);
    finalize_kernel<<<1, 128, 0, stream>>>(sf, gf, bef, sf + 256, sf + 384, 128, invN);
    head_out_kernel<<<(N + 3) / 4, 256, 0, stream>>>(HF, sf + 256, sf + 384, Wf2, bf2, out, N);
}

// Round 9
// 548.965 us; speedup vs baseline: 1.5281x; 1.0433x over previous
//
#include <hip/hip_runtime.h>

#define LRELU(x) ((x) > 0.0f ? (x) : 0.01f * (x))
#define UAF __uint_as_float

#if defined(__has_builtin)
#if __has_builtin(__builtin_amdgcn_fdot2_f32_bf16)
#define HAS_DOT2BF 1
#endif
#endif
#ifndef HAS_DOT2BF
#define HAS_DOT2BF 0
#endif

__device__ inline uint pack_bf16_rne(float x, float y) {
    uint lo = __float_as_uint(x);
    uint hi = __float_as_uint(y);
    lo = (lo + 0x7fffu + ((lo >> 16) & 1u)) >> 16;
    hi = (hi + 0x7fffu + ((hi >> 16) & 1u)) & 0xffff0000u;
    return lo | hi;
}

// c += dot(packed bf16 pair a, packed bf16 pair b)
__device__ inline float dot2bf(uint a, uint b, float c) {
#if HAS_DOT2BF
    typedef __bf16 bf16x2 __attribute__((ext_vector_type(2)));
    return __builtin_amdgcn_fdot2_f32_bf16(__builtin_bit_cast(bf16x2, a),
                                           __builtin_bit_cast(bf16x2, b), c, false);
#else
    c += UAF(a << 16) * UAF(b << 16);
    c += UAF(a & 0xffff0000u) * UAF(b & 0xffff0000u);
    return c;
#endif
}

__global__ void zero_kernel(float* p, int n) {
    int i = blockIdx.x * blockDim.x + threadIdx.x;
    if (i < n) p[i] = 0.0f;
}

// ---------- bucketed CSR build (r8, passing) ----------
__global__ __launch_bounds__(256) void bhist_kernel(const int* __restrict__ dst,
                                                    int* __restrict__ bcnt, int E, int NB) {
    __shared__ int h[512];
    for (int i = threadIdx.x; i < NB; i += 256) h[i] = 0;
    __syncthreads();
    int base = blockIdx.x * 8192;
    int end = min(E, base + 8192);
    for (int e = base + threadIdx.x; e < end; e += 256) atomicAdd(&h[dst[e] >> 8], 1);
    __syncthreads();
    for (int i = threadIdx.x; i < NB; i += 256)
        if (h[i]) atomicAdd(&bcnt[i], h[i]);
}

__global__ __launch_bounds__(512) void bscan_kernel(const int* __restrict__ bcnt,
                                                    int* __restrict__ boff,
                                                    int* __restrict__ bcur, int NB) {
    __shared__ int sh[512];
    int t = threadIdx.x;
    int v = (t < NB) ? bcnt[t] : 0;
    sh[t] = v;
    __syncthreads();
    for (int o = 1; o < 512; o <<= 1) {
        int u = (t >= o) ? sh[t - o] : 0;
        __syncthreads();
        sh[t] += u;
        __syncthreads();
    }
    if (t < NB) {
        boff[t] = sh[t] - v;
        bcur[t] = sh[t] - v;
    }
}

__global__ __launch_bounds__(256) void bscatter_kernel(const int* __restrict__ src,
                                                       const int* __restrict__ dst,
                                                       int* __restrict__ bcur,
                                                       uint* __restrict__ pairs, int E, int NB) {
    __shared__ int h[512];
    __shared__ int bbase[512];
    for (int i = threadIdx.x; i < NB; i += 256) h[i] = 0;
    __syncthreads();
    int base = blockIdx.x * 8192;
    int end = min(E, base + 8192);
    for (int e = base + threadIdx.x; e < end; e += 256) atomicAdd(&h[dst[e] >> 8], 1);
    __syncthreads();
    for (int i = threadIdx.x; i < NB; i += 256) {
        bbase[i] = h[i] ? atomicAdd(&bcur[i], h[i]) : 0;
        h[i] = 0;
    }
    __syncthreads();
    for (int e = base + threadIdx.x; e < end; e += 256) {
        int d = dst[e];
        int b = d >> 8;
        int o = atomicAdd(&h[b], 1);
        pairs[bbase[b] + o] = ((uint)src[e] << 8) | (uint)(d & 255);
    }
}

__global__ __launch_bounds__(256) void bcsr_kernel(const uint* __restrict__ pairs,
                                                   const int* __restrict__ boff,
                                                   int* __restrict__ ptr, int* __restrict__ cnt,
                                                   int* __restrict__ nbr, int N, int NB, int E) {
    __shared__ int h[256];
    __shared__ int sc[256];
    int b = blockIdx.x;
    int lo = boff[b];
    int hi = (b + 1 < NB) ? boff[b + 1] : E;
    int t = threadIdx.x;
    h[t] = 0;
    __syncthreads();
    for (int i = lo + t; i < hi; i += 256) atomicAdd(&h[pairs[i] & 255u], 1);
    __syncthreads();
    int v = h[t];
    sc[t] = v;
    __syncthreads();
    for (int o = 1; o < 256; o <<= 1) {
        int u = (t >= o) ? sc[t - o] : 0;
        __syncthreads();
        sc[t] += u;
        __syncthreads();
    }
    int excl = sc[t] - v;
    int node = (b << 8) + t;
    if (node < N) {
        ptr[node] = lo + excl;
        cnt[node] = v;
    }
    __syncthreads();
    h[t] = excl;
    __syncthreads();
    for (int i = lo + t; i < hi; i += 256) {
        uint p = pairs[i];
        int ld = p & 255u;
        int o = atomicAdd(&h[ld], 1);
        nbr[lo + o] = (int)(p >> 8);
    }
}

// ---------- fp32 -> packed bf16 table (layer 0 input) ----------
__global__ __launch_bounds__(256) void to_bf16_kernel(const float* __restrict__ in,
                                                      uint* __restrict__ table, int n8) {
    int i = blockIdx.x * blockDim.x + threadIdx.x;
    if (i >= n8) return;
    float4 a = *(const float4*)&in[(size_t)i * 8];
    float4 b = *(const float4*)&in[(size_t)i * 8 + 4];
    uint4 p = make_uint4(pack_bf16_rne(a.x, a.y), pack_bf16_rne(a.z, a.w),
                         pack_bf16_rne(b.x, b.y), pack_bf16_rne(b.z, b.w));
    *(uint4*)&table[(size_t)i * 4] = p;
}

// ---------- aggregation: one 64-lane wave per node; packed-bf16 in AND out ----------
template <bool ACT>
__global__ __launch_bounds__(256) void gather_kernel(
    const uint* __restrict__ tb, const int* __restrict__ ptr, const int* __restrict__ cnt,
    const int* __restrict__ nbr, const float* __restrict__ eps_gin, int layer,
    const float* __restrict__ scale, const float* __restrict__ shift, uint* __restrict__ agg,
    int N) {
    int gtid = blockIdx.x * blockDim.x + threadIdx.x;
    int node = gtid >> 6;
    if (node >= N) return;
    int lane = threadIdx.x & 63;
    int half = lane >> 5;
    int sl = lane & 31;
    float sc0 = 1.0f, sh0 = 0.0f, sc1 = 1.0f, sh1 = 0.0f;
    if (ACT) {
        sc0 = scale[2 * sl + 0];
        sh0 = shift[2 * sl + 0];
        sc1 = scale[2 * sl + 1];
        sh1 = shift[2 * sl + 1];
    }
    int start = ptr[node];
    int deg = cnt[node];
    float a0 = 0.0f, a1 = 0.0f;
    int j = half;
    for (; j + 6 < deg; j += 8) {
        int nA = nbr[start + j + 0];
        int nB = nbr[start + j + 2];
        int nC = nbr[start + j + 4];
        int nD = nbr[start + j + 6];
        uint vA = tb[(size_t)nA * 32 + sl];
        uint vB = tb[(size_t)nB * 32 + sl];
        uint vC = tb[(size_t)nC * 32 + sl];
        uint vD = tb[(size_t)nD * 32 + sl];
        float fA0 = UAF(vA << 16), fA1 = UAF(vA & 0xffff0000u);
        float fB0 = UAF(vB << 16), fB1 = UAF(vB & 0xffff0000u);
        float fC0 = UAF(vC << 16), fC1 = UAF(vC & 0xffff0000u);
        float fD0 = UAF(vD << 16), fD1 = UAF(vD & 0xffff0000u);
        if (ACT) {
            fA0 = LRELU(fA0 * sc0 + sh0);
            fA1 = LRELU(fA1 * sc1 + sh1);
            fB0 = LRELU(fB0 * sc0 + sh0);
            fB1 = LRELU(fB1 * sc1 + sh1);
            fC0 = LRELU(fC0 * sc0 + sh0);
            fC1 = LRELU(fC1 * sc1 + sh1);
            fD0 = LRELU(fD0 * sc0 + sh0);
            fD1 = LRELU(fD1 * sc1 + sh1);
        }
        a0 += (fA0 + fB0) + (fC0 + fD0);
        a1 += (fA1 + fB1) + (fC1 + fD1);
    }
    for (; j < deg; j += 2) {
        int nA = nbr[start + j];
        uint vA = tb[(size_t)nA * 32 + sl];
        float fA0 = UAF(vA << 16), fA1 = UAF(vA & 0xffff0000u);
        if (ACT) {
            fA0 = LRELU(fA0 * sc0 + sh0);
            fA1 = LRELU(fA1 * sc1 + sh1);
        }
        a0 += fA0;
        a1 += fA1;
    }
    a0 += __shfl(a0, lane ^ 32);
    a1 += __shfl(a1, lane ^ 32);
    uint vs = tb[(size_t)node * 32 + sl];
    float s0 = UAF(vs << 16), s1 = UAF(vs & 0xffff0000u);
    if (ACT) {
        s0 = LRELU(s0 * sc0 + sh0);
        s1 = LRELU(s1 * sc1 + sh1);
    }
    float ep = 1.0f + eps_gin[layer];
    a0 += ep * s0;
    a1 += ep * s1;
    if (half == 0) agg[(size_t)node * 32 + sl] = pack_bf16_rne(a0, a1);
}

__global__ void finalize_kernel(const float* __restrict__ sums, const float* __restrict__ g,
                                const float* __restrict__ be, float* __restrict__ scale,
                                float* __restrict__ shift, int C, float invN) {
    int d = threadIdx.x;
    if (d >= C) return;
    float mean = sums[d] * invN;
    float var = sums[C + d] * invN - mean * mean;
    float sc = g[d] * rsqrtf(var + 1e-5f);
    scale[d] = sc;
    shift[d] = be[d] - mean * sc;
}

// ---------- bf16 gemm: out(bf16) = act(in bf16) @ W + bias; optional fused col-stats ----------
// LDS halved vs fp32 (inT 8.7KB + W COLS/16 KB) -> 6 blocks/CU for COLS=64.
// MAC via v_dot2_f32_bf16 when available, unpack+FMA otherwise.
template <int COLS, int MINW>
__global__ __launch_bounds__(256, MINW) void gemm_bf16_kernel(
    const uint* __restrict__ in, const float* __restrict__ W, const float* __restrict__ bias,
    const float* __restrict__ scale, const float* __restrict__ shift, uint* __restrict__ out,
    float* __restrict__ sums, int nrows) {
    constexpr int NU = 32 * 68 + 32 * COLS;
    __shared__ uint smem[NU];
    uint* inT = smem;            // [kp][68] : idx kp*68 + row (16B-aligned rows)
    uint* wsb = smem + 32 * 68;  // [kp][COLS]
    int t = threadIdx.x;
    int row0 = blockIdx.x * 64;

    // stage 64 input rows (packed bf16), optional BN+LeakyReLU per element
    for (int i = 0; i < 2; i++) {
        int f = t + 256 * i;
        int r = f >> 3, q = f & 7;
        int gr = row0 + r;
        uint4 v = make_uint4(0, 0, 0, 0);
        if (gr < nrows) v = *(const uint4*)&in[(size_t)gr * 32 + q * 4];
        if (scale) {
            uint* pv = &v.x;
#pragma unroll
            for (int jq = 0; jq < 4; jq++) {
                int d = 8 * q + 2 * jq;
                float lo = UAF(pv[jq] << 16) * scale[d] + shift[d];
                float hi = UAF(pv[jq] & 0xffff0000u) * scale[d + 1] + shift[d + 1];
                lo = LRELU(lo);
                hi = LRELU(hi);
                pv[jq] = pack_bf16_rne(lo, hi);
            }
        }
        inT[(4 * q + 0) * 68 + r] = v.x;
        inT[(4 * q + 1) * 68 + r] = v.y;
        inT[(4 * q + 2) * 68 + r] = v.z;
        inT[(4 * q + 3) * 68 + r] = v.w;
    }
    // stage W packed (k-pairs)
    for (int i = 0; i < COLS / 8; i++) {
        int f = t + 256 * i;
        int kp = f / COLS, c = f % COLS;
        wsb[kp * COLS + c] =
            pack_bf16_rne(W[(size_t)(2 * kp) * COLS + c], W[(size_t)(2 * kp + 1) * COLS + c]);
    }
    __syncthreads();

    constexpr int NCH = COLS / 64;
    int rg = t >> 4, cg = t & 15;
    int r0 = rg * 4, c0 = cg * 4;
    float acc[4][NCH * 4];
#pragma unroll
    for (int r = 0; r < 4; r++)
#pragma unroll
        for (int c = 0; c < NCH * 4; c++) acc[r][c] = 0.0f;

#pragma unroll 8
    for (int kp = 0; kp < 32; kp++) {
        uint4 a = *(const uint4*)&inT[kp * 68 + r0];
        uint av[4] = {a.x, a.y, a.z, a.w};
#pragma unroll
        for (int jj = 0; jj < NCH; jj++) {
            uint4 w = *(const uint4*)&wsb[kp * COLS + c0 + jj * 64];
            uint wv[4] = {w.x, w.y, w.z, w.w};
#pragma unroll
            for (int r = 0; r < 4; r++)
#pragma unroll
                for (int c = 0; c < 4; c++)
                    acc[r][jj * 4 + c] = dot2bf(av[r], wv[c], acc[r][jj * 4 + c]);
        }
    }

    float ps[NCH * 4], ps2[NCH * 4];
#pragma unroll
    for (int c = 0; c < NCH * 4; c++) ps[c] = ps2[c] = 0.0f;
#pragma unroll
    for (int r = 0; r < 4; r++) {
        int gr = row0 + r0 + r;
        if (gr < nrows) {
#pragma unroll
            for (int jj = 0; jj < NCH; jj++) {
                float4 bv = *(const float4*)&bias[c0 + jj * 64];
                float o0 = acc[r][jj * 4 + 0] + bv.x;
                float o1 = acc[r][jj * 4 + 1] + bv.y;
                float o2 = acc[r][jj * 4 + 2] + bv.z;
                float o3 = acc[r][jj * 4 + 3] + bv.w;
                uint2 pk = make_uint2(pack_bf16_rne(o0, o1), pack_bf16_rne(o2, o3));
                *(uint2*)&out[(size_t)gr * (COLS / 2) + (c0 >> 1) + jj * 32] = pk;
                ps[jj * 4 + 0] += o0;
                ps2[jj * 4 + 0] += o0 * o0;
                ps[jj * 4 + 1] += o1;
                ps2[jj * 4 + 1] += o1 * o1;
                ps[jj * 4 + 2] += o2;
                ps2[jj * 4 + 2] += o2 * o2;
                ps[jj * 4 + 3] += o3;
                ps2[jj * 4 + 3] += o3 * o3;
            }
        }
    }

    if (sums == nullptr) return;

    __syncthreads();
    float* red = (float*)smem;  // 2*16*COLS floats <= smem size for COLS in {64,128}
    float* red2 = red + 16 * COLS;
#pragma unroll
    for (int jj = 0; jj < NCH; jj++) {
        *(float4*)&red[rg * COLS + c0 + jj * 64] = *(float4*)&ps[jj * 4];
        *(float4*)&red2[rg * COLS + c0 + jj * 64] = *(float4*)&ps2[jj * 4];
    }
    __syncthreads();
    if (t < COLS) {
        float s = 0.0f, s2 = 0.0f;
#pragma unroll
        for (int j = 0; j < 16; j++) {
            s += red[j * COLS + t];
            s2 += red2[j * COLS + t];
        }
        atomicAdd(&sums[t], s);
        atomicAdd(&sums[COLS + t], s2);
    }
}

// one wave per row; hf packed bf16 (128 features = 64 uints)
__global__ void head_out_kernel(const uint* __restrict__ hf, const float* __restrict__ scale,
                                const float* __restrict__ shift, const float* __restrict__ Wf2,
                                const float* __restrict__ bf2, float* __restrict__ out,
                                int nrows) {
    int gtid = blockIdx.x * blockDim.x + threadIdx.x;
    int wid = gtid >> 6;
    int l = threadIdx.x & 63;
    if (wid >= nrows) return;
    uint u = hf[(size_t)wid * 64 + l];
    float v0 = UAF(u << 16) * scale[2 * l] + shift[2 * l];
    float v1 = UAF(u & 0xffff0000u) * scale[2 * l + 1] + shift[2 * l + 1];
    v0 = LRELU(v0);
    v1 = LRELU(v1);
    float p = v0 * Wf2[2 * l] + v1 * Wf2[2 * l + 1];
    for (int o = 32; o > 0; o >>= 1) p += __shfl_down(p, o);
    if (l == 0) out[wid] = p + bf2[0];
}

extern "C" void kernel_launch(void* const* d_in, const int* in_sizes, int n_in, void* d_out,
                              int out_size, void* d_ws, size_t ws_size, hipStream_t stream) {
    const float* x = (const float*)d_in[0];
    const int* esrc = (const int*)d_in[1];
    const int* edst = (const int*)d_in[2];
    const float* W1 = (const float*)d_in[3];
    const float* b1 = (const float*)d_in[4];
    const float* g1 = (const float*)d_in[5];
    const float* be1 = (const float*)d_in[6];
    const float* W2 = (const float*)d_in[7];
    const float* b2 = (const float*)d_in[8];
    const float* eps_gin = (const float*)d_in[9];
    const float* g_bn = (const float*)d_in[10];
    const float* b_bn = (const float*)d_in[11];
    const float* Wf1 = (const float*)d_in[12];
    const float* bf1 = (const float*)d_in[13];
    const float* gf = (const float*)d_in[14];
    const float* bef = (const float*)d_in[15];
    const float* Wf2 = (const float*)d_in[16];
    const float* bf2 = (const float*)d_in[17];
    float* out = (float*)d_out;

    int N = in_sizes[0] / 64;
    int E = in_sizes[1];
    int NB = (N + 255) / 256;
    float invN = 1.0f / (float)N;

    float* ws = (float*)d_ws;
    size_t ND = (size_t)N * 64;
    // region A: packed bf16 table (lower half); pairs scratch upper half (CSR build only)
    uint* table = (uint*)ws;             // N*32 uints
    uint* pairs = (uint*)(ws + ND / 2);  // E uints
    uint* h1 = (uint*)(ws + ND);         // N*32 uints; later HF (N*64 uints spans region)
    uint* HF = h1;                       // head hidden packed (N*64 uints = full S1 region)
    uint* agg = (uint*)(ws + 2 * ND);    // N*32 uints
    float* stats = ws + 3 * ND;
    int* ibase = (int*)(stats + 3072);
    int* bcnt = ibase;
    int* bcur = ibase + 512;
    int* boff = ibase + 1024;
    int* cnt = ibase + 1536;
    int* ptr = cnt + N;
    int* nbr = ptr + N;

    zero_kernel<<<(3584 + 255) / 256, 256, 0, stream>>>(stats, 3584);

    int eb = (E + 8191) / 8192;
    bhist_kernel<<<eb, 256, 0, stream>>>(edst, bcnt, E, NB);
    bscan_kernel<<<1, 512, 0, stream>>>(bcnt, boff, bcur, NB);
    bscatter_kernel<<<eb, 256, 0, stream>>>(esrc, edst, bcur, pairs, E, NB);
    bcsr_kernel<<<NB, 256, 0, stream>>>(pairs, boff, ptr, cnt, nbr, N, NB, E);

    int n8 = N * 8;
    int gg = (N + 63) / 64;
    int gblocks = (N * 64 + 255) / 256;
    to_bf16_kernel<<<(n8 + 255) / 256, 256, 0, stream>>>(x, table, n8);

    for (int i = 0; i < 3; i++) {
        float* st = stats + (size_t)(2 * i) * 512;      // inner BN sums
        float* so = stats + (size_t)(2 * i + 1) * 512;  // outer BN sums (layers 0,1)
        if (i == 0) {
            gather_kernel<false><<<gblocks, 256, 0, stream>>>(table, ptr, cnt, nbr, eps_gin, i,
                                                              nullptr, nullptr, agg, N);
        } else {
            float* sp = stats + (size_t)(2 * (i - 1) + 1) * 512;
            gather_kernel<true><<<gblocks, 256, 0, stream>>>(table, ptr, cnt, nbr, eps_gin, i,
                                                             sp + 256, sp + 384, agg, N);
        }
        gemm_bf16_kernel<64, 6><<<gg, 256, 0, stream>>>(agg, W1 + (size_t)i * 4096,
                                                        b1 + (size_t)i * 64, nullptr, nullptr,
                                                        h1, st, N);
        finalize_kernel<<<1, 64, 0, stream>>>(st, g1 + (size_t)i * 64, be1 + (size_t)i * 64,
                                              st + 256, st + 384, 64, invN);
        gemm_bf16_kernel<64, 6><<<gg, 256, 0, stream>>>(h1, W2 + (size_t)i * 4096,
                                                        b2 + (size_t)i * 64, st + 256, st + 384,
                                                        table, (i < 2) ? so : nullptr, N);
        if (i < 2) {
            finalize_kernel<<<1, 64, 0, stream>>>(so, g_bn + (size_t)i * 64,
                                                  b_bn + (size_t)i * 64, so + 256, so + 384, 64,
                                                  invN);
        }
    }

    float* sf = stats + (size_t)5 * 512;
    gemm_bf16_kernel<128, 4><<<gg, 256, 0, stream>>>(table, Wf1, bf1, nullptr, nullptr, HF, sf,
                                                     N);
    finalize_kernel<<<1, 128, 0, stream>>>(sf, gf, bef, sf + 256, sf + 384, 128, invN);
    head_out_kernel<<<(N + 3) / 4, 256, 0, stream>>>(HF, sf + 256, sf + 384, Wf2, bf2, out, N);
}

// Round 11
// 541.363 us; speedup vs baseline: 1.5496x; 1.0140x over previous
//
#include <hip/hip_runtime.h>

#define LRELU(x) ((x) > 0.0f ? (x) : 0.01f * (x))
#define UAF __uint_as_float

#if defined(__has_builtin)
#if __has_builtin(__builtin_amdgcn_fdot2_f32_bf16)
#define HAS_DOT2BF 1
#endif
#endif
#ifndef HAS_DOT2BF
#define HAS_DOT2BF 0
#endif

__device__ inline uint pack_bf16_rne(float x, float y) {
    uint lo = __float_as_uint(x);
    uint hi = __float_as_uint(y);
    lo = (lo + 0x7fffu + ((lo >> 16) & 1u)) >> 16;
    hi = (hi + 0x7fffu + ((hi >> 16) & 1u)) & 0xffff0000u;
    return lo | hi;
}

__device__ inline float dot2bf(uint a, uint b, float c) {
#if HAS_DOT2BF
    typedef __bf16 bf16x2 __attribute__((ext_vector_type(2)));
    return __builtin_amdgcn_fdot2_f32_bf16(__builtin_bit_cast(bf16x2, a),
                                           __builtin_bit_cast(bf16x2, b), c, false);
#else
    c += UAF(a << 16) * UAF(b << 16);
    c += UAF(a & 0xffff0000u) * UAF(b & 0xffff0000u);
    return c;
#endif
}

// BN scale/shift for feature d from raw sums (same formula as the old finalize_kernel)
__device__ inline void bn_coef(const float* __restrict__ sums, int C, int d,
                               const float* __restrict__ g, const float* __restrict__ be,
                               float invN, float& sc, float& sh) {
    float mean = sums[d] * invN;
    float var = sums[C + d] * invN - mean * mean;
    sc = g[d] * rsqrtf(var + 1e-5f);
    sh = be[d] - mean * sc;
}

__global__ void zero_kernel(float* p, int n) {
    int i = blockIdx.x * blockDim.x + threadIdx.x;
    if (i < n) p[i] = 0.0f;
}

// ---------- bucketed CSR build (r8, passing) ----------
__global__ __launch_bounds__(256) void bhist_kernel(const int* __restrict__ dst,
                                                    int* __restrict__ bcnt, int E, int NB) {
    __shared__ int h[512];
    for (int i = threadIdx.x; i < NB; i += 256) h[i] = 0;
    __syncthreads();
    int base = blockIdx.x * 8192;
    int end = min(E, base + 8192);
    for (int e = base + threadIdx.x; e < end; e += 256) atomicAdd(&h[dst[e] >> 8], 1);
    __syncthreads();
    for (int i = threadIdx.x; i < NB; i += 256)
        if (h[i]) atomicAdd(&bcnt[i], h[i]);
}

__global__ __launch_bounds__(512) void bscan_kernel(const int* __restrict__ bcnt,
                                                    int* __restrict__ boff,
                                                    int* __restrict__ bcur, int NB) {
    __shared__ int sh[512];
    int t = threadIdx.x;
    int v = (t < NB) ? bcnt[t] : 0;
    sh[t] = v;
    __syncthreads();
    for (int o = 1; o < 512; o <<= 1) {
        int u = (t >= o) ? sh[t - o] : 0;
        __syncthreads();
        sh[t] += u;
        __syncthreads();
    }
    if (t < NB) {
        boff[t] = sh[t] - v;
        bcur[t] = sh[t] - v;
    }
}

__global__ __launch_bounds__(256) void bscatter_kernel(const int* __restrict__ src,
                                                       const int* __restrict__ dst,
                                                       int* __restrict__ bcur,
                                                       uint* __restrict__ pairs, int E, int NB) {
    __shared__ int h[512];
    __shared__ int bbase[512];
    for (int i = threadIdx.x; i < NB; i += 256) h[i] = 0;
    __syncthreads();
    int base = blockIdx.x * 8192;
    int end = min(E, base + 8192);
    for (int e = base + threadIdx.x; e < end; e += 256) atomicAdd(&h[dst[e] >> 8], 1);
    __syncthreads();
    for (int i = threadIdx.x; i < NB; i += 256) {
        bbase[i] = h[i] ? atomicAdd(&bcur[i], h[i]) : 0;
        h[i] = 0;
    }
    __syncthreads();
    for (int e = base + threadIdx.x; e < end; e += 256) {
        int d = dst[e];
        int b = d >> 8;
        int o = atomicAdd(&h[b], 1);
        pairs[bbase[b] + o] = ((uint)src[e] << 8) | (uint)(d & 255);
    }
}

__global__ __launch_bounds__(256) void bcsr_kernel(const uint* __restrict__ pairs,
                                                   const int* __restrict__ boff,
                                                   int* __restrict__ ptr, int* __restrict__ cnt,
                                                   int* __restrict__ nbr, int N, int NB, int E) {
    __shared__ int h[256];
    __shared__ int sc[256];
    int b = blockIdx.x;
    int lo = boff[b];
    int hi = (b + 1 < NB) ? boff[b + 1] : E;
    int t = threadIdx.x;
    h[t] = 0;
    __syncthreads();
    for (int i = lo + t; i < hi; i += 256) atomicAdd(&h[pairs[i] & 255u], 1);
    __syncthreads();
    int v = h[t];
    sc[t] = v;
    __syncthreads();
    for (int o = 1; o < 256; o <<= 1) {
        int u = (t >= o) ? sc[t - o] : 0;
        __syncthreads();
        sc[t] += u;
        __syncthreads();
    }
    int excl = sc[t] - v;
    int node = (b << 8) + t;
    if (node < N) {
        ptr[node] = lo + excl;
        cnt[node] = v;
    }
    __syncthreads();
    h[t] = excl;
    __syncthreads();
    for (int i = lo + t; i < hi; i += 256) {
        uint p = pairs[i];
        int ld = p & 255u;
        int o = atomicAdd(&h[ld], 1);
        nbr[lo + o] = (int)(p >> 8);
    }
}

// ---------- fp32 -> packed bf16 table (layer 0 input) ----------
__global__ __launch_bounds__(256) void to_bf16_kernel(const float* __restrict__ in,
                                                      uint* __restrict__ table, int n8) {
    int i = blockIdx.x * blockDim.x + threadIdx.x;
    if (i >= n8) return;
    float4 a = *(const float4*)&in[(size_t)i * 8];
    float4 b = *(const float4*)&in[(size_t)i * 8 + 4];
    uint4 p = make_uint4(pack_bf16_rne(a.x, a.y), pack_bf16_rne(a.z, a.w),
                         pack_bf16_rne(b.x, b.y), pack_bf16_rne(b.z, b.w));
    *(uint4*)&table[(size_t)i * 4] = p;
}

// ---------- aggregation: one 64-lane wave per node; packed-bf16 in and out ----------
template <bool ACT>
__global__ __launch_bounds__(256) void gather_kernel(
    const uint* __restrict__ tb, const int* __restrict__ ptr, const int* __restrict__ cnt,
    const int* __restrict__ nbr, const float* __restrict__ eps_gin, int layer,
    const float* __restrict__ g, const float* __restrict__ be,
    const float* __restrict__ sums, float invN, uint* __restrict__ agg, int N) {
    int gtid = blockIdx.x * blockDim.x + threadIdx.x;
    int node = gtid >> 6;
    if (node >= N) return;
    int lane = threadIdx.x & 63;
    int half = lane >> 5;
    int sl = lane & 31;
    float sc0 = 1.0f, sh0 = 0.0f, sc1 = 1.0f, sh1 = 0.0f;
    if (ACT) {
        bn_coef(sums, 64, 2 * sl + 0, g, be, invN, sc0, sh0);
        bn_coef(sums, 64, 2 * sl + 1, g, be, invN, sc1, sh1);
    }
    int start = ptr[node];
    int deg = cnt[node];
    float a0 = 0.0f, a1 = 0.0f;
    int j = half;
    for (; j + 14 < deg; j += 16) {  // 8 independent row loads per half
        int ni[8];
        uint vv[8];
#pragma unroll
        for (int q = 0; q < 8; q++) ni[q] = nbr[start + j + 2 * q];
#pragma unroll
        for (int q = 0; q < 8; q++) vv[q] = tb[(size_t)ni[q] * 32 + sl];
#pragma unroll
        for (int q = 0; q < 8; q++) {
            float f0 = UAF(vv[q] << 16), f1 = UAF(vv[q] & 0xffff0000u);
            if (ACT) {
                f0 = LRELU(f0 * sc0 + sh0);
                f1 = LRELU(f1 * sc1 + sh1);
            }
            a0 += f0;
            a1 += f1;
        }
    }
    for (; j + 6 < deg; j += 8) {
        int ni[4];
        uint vv[4];
#pragma unroll
        for (int q = 0; q < 4; q++) ni[q] = nbr[start + j + 2 * q];
#pragma unroll
        for (int q = 0; q < 4; q++) vv[q] = tb[(size_t)ni[q] * 32 + sl];
#pragma unroll
        for (int q = 0; q < 4; q++) {
            float f0 = UAF(vv[q] << 16), f1 = UAF(vv[q] & 0xffff0000u);
            if (ACT) {
                f0 = LRELU(f0 * sc0 + sh0);
                f1 = LRELU(f1 * sc1 + sh1);
            }
            a0 += f0;
            a1 += f1;
        }
    }
    for (; j < deg; j += 2) {
        uint vA = tb[(size_t)nbr[start + j] * 32 + sl];
        float f0 = UAF(vA << 16), f1 = UAF(vA & 0xffff0000u);
        if (ACT) {
            f0 = LRELU(f0 * sc0 + sh0);
            f1 = LRELU(f1 * sc1 + sh1);
        }
        a0 += f0;
        a1 += f1;
    }
    a0 += __shfl(a0, lane ^ 32);
    a1 += __shfl(a1, lane ^ 32);
    uint vs = tb[(size_t)node * 32 + sl];
    float s0 = UAF(vs << 16), s1 = UAF(vs & 0xffff0000u);
    if (ACT) {
        s0 = LRELU(s0 * sc0 + sh0);
        s1 = LRELU(s1 * sc1 + sh1);
    }
    float ep = 1.0f + eps_gin[layer];
    a0 += ep * s0;
    a1 += ep * s1;
    if (half == 0) agg[(size_t)node * 32 + sl] = pack_bf16_rne(a0, a1);
}

// ---------- bf16-dot gemm (COLS=64): input either packed bf16 (agg) or fp32+inline-BN
// (h1, packed ONCE after BN -> removes double rounding); output bf16 table or fp32 ----------
template <bool INBN, bool OUTB, int MINW>
__global__ __launch_bounds__(256, MINW) void gemm_bf16_kernel(
    const uint* __restrict__ inb, const float* __restrict__ inf, const float* __restrict__ W,
    const float* __restrict__ bias, const float* __restrict__ g, const float* __restrict__ be,
    const float* __restrict__ bsums, float invN, uint* __restrict__ outb,
    float* __restrict__ outf, float* __restrict__ sums, int nrows) {
    constexpr int COLS = 64;
    __shared__ uint smem[32 * 68 + 32 * COLS];
    uint* inT = smem;
    uint* wsb = smem + 32 * 68;
    int t = threadIdx.x;
    int row0 = blockIdx.x * 64;

    if (!INBN) {
        for (int i = 0; i < 2; i++) {
            int f = t + 256 * i;
            int r = f >> 3, q = f & 7;
            int gr = row0 + r;
            uint4 v = make_uint4(0, 0, 0, 0);
            if (gr < nrows) v = *(const uint4*)&inb[(size_t)gr * 32 + q * 4];
            inT[(4 * q + 0) * 68 + r] = v.x;
            inT[(4 * q + 1) * 68 + r] = v.y;
            inT[(4 * q + 2) * 68 + r] = v.z;
            inT[(4 * q + 3) * 68 + r] = v.w;
        }
    } else {
        for (int i = 0; i < 4; i++) {
            int f = t + 256 * i;
            int r = f >> 4, q = f & 15;  // q: float4 chunk (features 4q..4q+3)
            int gr = row0 + r;
            float4 v = make_float4(0.f, 0.f, 0.f, 0.f);
            if (gr < nrows) v = *(const float4*)&inf[(size_t)gr * 64 + q * 4];
            int d = 4 * q;
            float sc0, sh0, sc1, sh1, sc2, sh2, sc3, sh3;
            bn_coef(bsums, 64, d + 0, g, be, invN, sc0, sh0);
            bn_coef(bsums, 64, d + 1, g, be, invN, sc1, sh1);
            bn_coef(bsums, 64, d + 2, g, be, invN, sc2, sh2);
            bn_coef(bsums, 64, d + 3, g, be, invN, sc3, sh3);
            float e0 = LRELU(v.x * sc0 + sh0);
            float e1 = LRELU(v.y * sc1 + sh1);
            float e2 = LRELU(v.z * sc2 + sh2);
            float e3 = LRELU(v.w * sc3 + sh3);
            inT[(2 * q + 0) * 68 + r] = pack_bf16_rne(e0, e1);
            inT[(2 * q + 1) * 68 + r] = pack_bf16_rne(e2, e3);
        }
    }
    for (int i = 0; i < COLS / 8; i++) {
        int f = t + 256 * i;
        int kp = f / COLS, c = f % COLS;
        wsb[kp * COLS + c] =
            pack_bf16_rne(W[(size_t)(2 * kp) * COLS + c], W[(size_t)(2 * kp + 1) * COLS + c]);
    }
    __syncthreads();

    int rg = t >> 4, cg = t & 15;
    int r0 = rg * 4, c0 = cg * 4;
    float acc[4][4];
#pragma unroll
    for (int r = 0; r < 4; r++)
#pragma unroll
        for (int c = 0; c < 4; c++) acc[r][c] = 0.0f;

#pragma unroll 8
    for (int kp = 0; kp < 32; kp++) {
        uint4 a = *(const uint4*)&inT[kp * 68 + r0];
        uint av[4] = {a.x, a.y, a.z, a.w};
        uint4 w = *(const uint4*)&wsb[kp * COLS + c0];
        uint wv[4] = {w.x, w.y, w.z, w.w};
#pragma unroll
        for (int r = 0; r < 4; r++)
#pragma unroll
            for (int c = 0; c < 4; c++) acc[r][c] = dot2bf(av[r], wv[c], acc[r][c]);
    }

    float ps[4], ps2[4];
#pragma unroll
    for (int c = 0; c < 4; c++) ps[c] = ps2[c] = 0.0f;
    float4 bv = *(const float4*)&bias[c0];
#pragma unroll
    for (int r = 0; r < 4; r++) {
        int gr = row0 + r0 + r;
        if (gr < nrows) {
            float o0 = acc[r][0] + bv.x;
            float o1 = acc[r][1] + bv.y;
            float o2 = acc[r][2] + bv.z;
            float o3 = acc[r][3] + bv.w;
            if (OUTB) {
                uint2 pk = make_uint2(pack_bf16_rne(o0, o1), pack_bf16_rne(o2, o3));
                *(uint2*)&outb[(size_t)gr * 32 + (c0 >> 1)] = pk;
            } else {
                *(float4*)&outf[(size_t)gr * 64 + c0] = make_float4(o0, o1, o2, o3);
            }
            ps[0] += o0;
            ps2[0] += o0 * o0;
            ps[1] += o1;
            ps2[1] += o1 * o1;
            ps[2] += o2;
            ps2[2] += o2 * o2;
            ps[3] += o3;
            ps2[3] += o3 * o3;
        }
    }

    if (sums == nullptr) return;

    __syncthreads();
    float* red = (float*)smem;
    float* red2 = red + 16 * COLS;
    *(float4*)&red[rg * COLS + c0] = *(float4*)&ps[0];
    *(float4*)&red2[rg * COLS + c0] = *(float4*)&ps2[0];
    __syncthreads();
    if (t < COLS) {
        float s = 0.0f, s2 = 0.0f;
#pragma unroll
        for (int j = 0; j < 16; j++) {
            s += red[j * COLS + t];
            s2 += red2[j * COLS + t];
        }
        atomicAdd(&sums[t], s);
        atomicAdd(&sums[COLS + t], s2);
    }
}

// ---------- head gemm, full fp32 (r8 lineage): HF = X @ Wf1 + bf1, fused col-stats ----------
__global__ __launch_bounds__(256, 4) void gemm_f32_head_kernel(const float* __restrict__ in,
                                                               const float* __restrict__ W,
                                                               const float* __restrict__ bias,
                                                               float* __restrict__ out,
                                                               float* __restrict__ sums,
                                                               int nrows) {
    constexpr int COLS = 128;
    __shared__ float inT[64][68];
    __shared__ float ws[64][COLS];
    int t = threadIdx.x;
    int row0 = blockIdx.x * 64;

    for (int i = 0; i < 4; i++) {
        int f = t + 256 * i;
        int r = f >> 4, ch = f & 15;
        int gr = row0 + r;
        float4 v = make_float4(0.f, 0.f, 0.f, 0.f);
        if (gr < nrows) v = *(const float4*)&in[(size_t)gr * 64 + ch * 4];
        inT[ch * 4 + 0][r] = v.x;
        inT[ch * 4 + 1][r] = v.y;
        inT[ch * 4 + 2][r] = v.z;
        inT[ch * 4 + 3][r] = v.w;
    }
    for (int i = 0; i < COLS / 16; i++) {
        int f = t + 256 * i;
        int k = f / (COLS / 4), c4 = f % (COLS / 4);
        *(float4*)&ws[k][c4 * 4] = *(const float4*)&W[(size_t)k * COLS + c4 * 4];
    }
    __syncthreads();

    int rg = t >> 4, cg = t & 15;
    int r0 = rg * 4, c0 = cg * 4;
    float acc[4][8];
#pragma unroll
    for (int r = 0; r < 4; r++)
#pragma unroll
        for (int c = 0; c < 8; c++) acc[r][c] = 0.0f;

#pragma unroll 16
    for (int k = 0; k < 64; k++) {
        float4 a = *(const float4*)&inT[k][r0];
        float ar[4] = {a.x, a.y, a.z, a.w};
#pragma unroll
        for (int jj = 0; jj < 2; jj++) {
            float4 w4 = *(const float4*)&ws[k][c0 + jj * 64];
            float wr[4] = {w4.x, w4.y, w4.z, w4.w};
#pragma unroll
            for (int r = 0; r < 4; r++)
#pragma unroll
                for (int c = 0; c < 4; c++) acc[r][jj * 4 + c] += ar[r] * wr[c];
        }
    }

    float ps[8], ps2[8];
#pragma unroll
    for (int c = 0; c < 8; c++) ps[c] = ps2[c] = 0.0f;
#pragma unroll
    for (int r = 0; r < 4; r++) {
        int gr = row0 + r0 + r;
        if (gr < nrows) {
#pragma unroll
            for (int jj = 0; jj < 2; jj++) {
                float4 bv = *(const float4*)&bias[c0 + jj * 64];
                float4 o = make_float4(acc[r][jj * 4 + 0] + bv.x, acc[r][jj * 4 + 1] + bv.y,
                                       acc[r][jj * 4 + 2] + bv.z, acc[r][jj * 4 + 3] + bv.w);
                *(float4*)&out[(size_t)gr * COLS + c0 + jj * 64] = o;
                ps[jj * 4 + 0] += o.x;
                ps2[jj * 4 + 0] += o.x * o.x;
                ps[jj * 4 + 1] += o.y;
                ps2[jj * 4 + 1] += o.y * o.y;
                ps[jj * 4 + 2] += o.z;
                ps2[jj * 4 + 2] += o.z * o.z;
                ps[jj * 4 + 3] += o.w;
                ps2[jj * 4 + 3] += o.w * o.w;
            }
        }
    }

    __syncthreads();
    float* red = &inT[0][0];
    float* red2 = red + 16 * COLS;
#pragma unroll
    for (int jj = 0; jj < 2; jj++) {
        *(float4*)&red[rg * COLS + c0 + jj * 64] = *(float4*)&ps[jj * 4];
        *(float4*)&red2[rg * COLS + c0 + jj * 64] = *(float4*)&ps2[jj * 4];
    }
    __syncthreads();
    if (t < COLS) {
        float s = 0.0f, s2 = 0.0f;
#pragma unroll
        for (int j = 0; j < 16; j++) {
            s += red[j * COLS + t];
            s2 += red2[j * COLS + t];
        }
        atomicAdd(&sums[t], s);
        atomicAdd(&sums[COLS + t], s2);
    }
}

// one wave per row; hf fp32 (N x 128); head BN inline from sums
__global__ void head_out_kernel(const float* __restrict__ hf, const float* __restrict__ g,
                                const float* __restrict__ be, const float* __restrict__ sums,
                                float invN, const float* __restrict__ Wf2,
                                const float* __restrict__ bf2, float* __restrict__ out,
                                int nrows) {
    int gtid = blockIdx.x * blockDim.x + threadIdx.x;
    int wid = gtid >> 6;
    int l = threadIdx.x & 63;
    if (wid >= nrows) return;
    float sc0, sh0, sc1, sh1;
    bn_coef(sums, 128, l, g, be, invN, sc0, sh0);
    bn_coef(sums, 128, 64 + l, g, be, invN, sc1, sh1);
    float v0 = hf[(size_t)wid * 128 + l];
    float v1 = hf[(size_t)wid * 128 + 64 + l];
    v0 = LRELU(v0 * sc0 + sh0);
    v1 = LRELU(v1 * sc1 + sh1);
    float p = v0 * Wf2[l] + v1 * Wf2[64 + l];
    for (int o = 32; o > 0; o >>= 1) p += __shfl_down(p, o);
    if (l == 0) out[wid] = p + bf2[0];
}

extern "C" void kernel_launch(void* const* d_in, const int* in_sizes, int n_in, void* d_out,
                              int out_size, void* d_ws, size_t ws_size, hipStream_t stream) {
    const float* x = (const float*)d_in[0];
    const int* esrc = (const int*)d_in[1];
    const int* edst = (const int*)d_in[2];
    const float* W1 = (const float*)d_in[3];
    const float* b1 = (const float*)d_in[4];
    const float* g1 = (const float*)d_in[5];
    const float* be1 = (const float*)d_in[6];
    const float* W2 = (const float*)d_in[7];
    const float* b2 = (const float*)d_in[8];
    const float* eps_gin = (const float*)d_in[9];
    const float* g_bn = (const float*)d_in[10];
    const float* b_bn = (const float*)d_in[11];
    const float* Wf1 = (const float*)d_in[12];
    const float* bf1 = (const float*)d_in[13];
    const float* gf = (const float*)d_in[14];
    const float* bef = (const float*)d_in[15];
    const float* Wf2 = (const float*)d_in[16];
    const float* bf2 = (const float*)d_in[17];
    float* out = (float*)d_out;

    int N = in_sizes[0] / 64;
    int E = in_sizes[1];
    int NB = (N + 255) / 256;
    float invN = 1.0f / (float)N;

    float* ws = (float*)d_ws;
    size_t ND = (size_t)N * 64;
    // region A (ND floats): table bf16 (lower half) + pairs (upper, build-only);
    //   after layer-2 gather the table is dead -> X fp32 takes the full region.
    uint* table = (uint*)ws;
    uint* pairs = (uint*)(ws + ND / 2);
    float* X = ws;
    // region B (ND floats): h1 fp32
    float* h1 = ws + ND;
    // region C (ND floats): agg bf16 (lower half)
    uint* agg = (uint*)(ws + 2 * ND);
    // HF fp32 (2*ND floats) spans regions B+C after h1/agg are dead
    float* HF = ws + ND;
    float* stats = ws + 3 * ND;
    int* ibase = (int*)(stats + 3072);
    int* bcnt = ibase;
    int* bcur = ibase + 512;
    int* boff = ibase + 1024;
    int* cnt = ibase + 1536;
    int* ptr = cnt + N;
    int* nbr = ptr + N;

    zero_kernel<<<(3584 + 255) / 256, 256, 0, stream>>>(stats, 3584);

    int eb = (E + 8191) / 8192;
    bhist_kernel<<<eb, 256, 0, stream>>>(edst, bcnt, E, NB);
    bscan_kernel<<<1, 512, 0, stream>>>(bcnt, boff, bcur, NB);
    bscatter_kernel<<<eb, 256, 0, stream>>>(esrc, edst, bcur, pairs, E, NB);
    bcsr_kernel<<<NB, 256, 0, stream>>>(pairs, boff, ptr, cnt, nbr, N, NB, E);

    int n8 = N * 8;
    int gg = (N + 63) / 64;
    int gblocks = (N * 64 + 255) / 256;
    to_bf16_kernel<<<(n8 + 255) / 256, 256, 0, stream>>>(x, table, n8);

    for (int i = 0; i < 3; i++) {
        float* st = stats + (size_t)(2 * i) * 512;      // inner BN sums
        float* so = stats + (size_t)(2 * i + 1) * 512;  // outer BN sums (layers 0,1)
        if (i == 0) {
            gather_kernel<false><<<gblocks, 256, 0, stream>>>(table, ptr, cnt, nbr, eps_gin, i,
                                                              nullptr, nullptr, nullptr, invN,
                                                              agg, N);
        } else {
            float* sp = stats + (size_t)(2 * (i - 1) + 1) * 512;
            gather_kernel<true><<<gblocks, 256, 0, stream>>>(
                table, ptr, cnt, nbr, eps_gin, i, g_bn + (size_t)(i - 1) * 64,
                b_bn + (size_t)(i - 1) * 64, sp, invN, agg, N);
        }
        // gemm1: agg(bf16) @ W1 -> h1 fp32 (+inner stats)
        gemm_bf16_kernel<false, false, 6><<<gg, 256, 0, stream>>>(
            agg, nullptr, W1 + (size_t)i * 4096, b1 + (size_t)i * 64, nullptr, nullptr, nullptr,
            invN, nullptr, h1, st, N);
        // gemm2: BN(h1 fp32)+lrelu packed once -> @ W2 -> table bf16 (L0,1) / X fp32 (L2)
        if (i < 2) {
            gemm_bf16_kernel<true, true, 6><<<gg, 256, 0, stream>>>(
                nullptr, h1, W2 + (size_t)i * 4096, b2 + (size_t)i * 64, g1 + (size_t)i * 64,
                be1 + (size_t)i * 64, st, invN, table, nullptr, so, N);
        } else {
            gemm_bf16_kernel<true, false, 6><<<gg, 256, 0, stream>>>(
                nullptr, h1, W2 + (size_t)i * 4096, b2 + (size_t)i * 64, g1 + (size_t)i * 64,
                be1 + (size_t)i * 64, st, invN, nullptr, X, nullptr, N);
        }
    }

    float* sf = stats + (size_t)5 * 512;
    gemm_f32_head_kernel<<<gg, 256, 0, stream>>>(X, Wf1, bf1, HF, sf, N);
    head_out_kernel<<<(N + 3) / 4, 256, 0, stream>>>(HF, gf, bef, sf, invN, Wf2, bf2, out, N);
}

// Round 12
// 382.234 us; speedup vs baseline: 2.1947x; 1.4163x over previous
//
#include <hip/hip_runtime.h>

#define LRELU(x) ((x) > 0.0f ? (x) : 0.01f * (x))
#define UAF __uint_as_float
#define NSLOT 16

#if defined(__has_builtin)
#if __has_builtin(__builtin_amdgcn_fdot2_f32_bf16)
#define HAS_DOT2BF 1
#endif
#endif
#ifndef HAS_DOT2BF
#define HAS_DOT2BF 0
#endif

__device__ inline uint pack_bf16_rne(float x, float y) {
    uint lo = __float_as_uint(x);
    uint hi = __float_as_uint(y);
    lo = (lo + 0x7fffu + ((lo >> 16) & 1u)) >> 16;
    hi = (hi + 0x7fffu + ((hi >> 16) & 1u)) & 0xffff0000u;
    return lo | hi;
}

__device__ inline float dot2bf(uint a, uint b, float c) {
#if HAS_DOT2BF
    typedef __bf16 bf16x2 __attribute__((ext_vector_type(2)));
    return __builtin_amdgcn_fdot2_f32_bf16(__builtin_bit_cast(bf16x2, a),
                                           __builtin_bit_cast(bf16x2, b), c, false);
#else
    c += UAF(a << 16) * UAF(b << 16);
    c += UAF(a & 0xffff0000u) * UAF(b & 0xffff0000u);
    return c;
#endif
}

__global__ void zero_kernel(float* p, int n) {
    int i = blockIdx.x * blockDim.x + threadIdx.x;
    if (i < n) p[i] = 0.0f;
}

// ---------- bucketed CSR build (r8, passing) ----------
__global__ __launch_bounds__(256) void bhist_kernel(const int* __restrict__ dst,
                                                    int* __restrict__ bcnt, int E, int NB) {
    __shared__ int h[512];
    for (int i = threadIdx.x; i < NB; i += 256) h[i] = 0;
    __syncthreads();
    int base = blockIdx.x * 8192;
    int end = min(E, base + 8192);
    for (int e = base + threadIdx.x; e < end; e += 256) atomicAdd(&h[dst[e] >> 8], 1);
    __syncthreads();
    for (int i = threadIdx.x; i < NB; i += 256)
        if (h[i]) atomicAdd(&bcnt[i], h[i]);
}

__global__ __launch_bounds__(512) void bscan_kernel(const int* __restrict__ bcnt,
                                                    int* __restrict__ boff,
                                                    int* __restrict__ bcur, int NB) {
    __shared__ int sh[512];
    int t = threadIdx.x;
    int v = (t < NB) ? bcnt[t] : 0;
    sh[t] = v;
    __syncthreads();
    for (int o = 1; o < 512; o <<= 1) {
        int u = (t >= o) ? sh[t - o] : 0;
        __syncthreads();
        sh[t] += u;
        __syncthreads();
    }
    if (t < NB) {
        boff[t] = sh[t] - v;
        bcur[t] = sh[t] - v;
    }
}

__global__ __launch_bounds__(256) void bscatter_kernel(const int* __restrict__ src,
                                                       const int* __restrict__ dst,
                                                       int* __restrict__ bcur,
                                                       uint* __restrict__ pairs, int E, int NB) {
    __shared__ int h[512];
    __shared__ int bbase[512];
    for (int i = threadIdx.x; i < NB; i += 256) h[i] = 0;
    __syncthreads();
    int base = blockIdx.x * 8192;
    int end = min(E, base + 8192);
    for (int e = base + threadIdx.x; e < end; e += 256) atomicAdd(&h[dst[e] >> 8], 1);
    __syncthreads();
    for (int i = threadIdx.x; i < NB; i += 256) {
        bbase[i] = h[i] ? atomicAdd(&bcur[i], h[i]) : 0;
        h[i] = 0;
    }
    __syncthreads();
    for (int e = base + threadIdx.x; e < end; e += 256) {
        int d = dst[e];
        int b = d >> 8;
        int o = atomicAdd(&h[b], 1);
        pairs[bbase[b] + o] = ((uint)src[e] << 8) | (uint)(d & 255);
    }
}

__global__ __launch_bounds__(256) void bcsr_kernel(const uint* __restrict__ pairs,
                                                   const int* __restrict__ boff,
                                                   int* __restrict__ ptr, int* __restrict__ cnt,
                                                   int* __restrict__ nbr, int N, int NB, int E) {
    __shared__ int h[256];
    __shared__ int sc[256];
    int b = blockIdx.x;
    int lo = boff[b];
    int hi = (b + 1 < NB) ? boff[b + 1] : E;
    int t = threadIdx.x;
    h[t] = 0;
    __syncthreads();
    for (int i = lo + t; i < hi; i += 256) atomicAdd(&h[pairs[i] & 255u], 1);
    __syncthreads();
    int v = h[t];
    sc[t] = v;
    __syncthreads();
    for (int o = 1; o < 256; o <<= 1) {
        int u = (t >= o) ? sc[t - o] : 0;
        __syncthreads();
        sc[t] += u;
        __syncthreads();
    }
    int excl = sc[t] - v;
    int node = (b << 8) + t;
    if (node < N) {
        ptr[node] = lo + excl;
        cnt[node] = v;
    }
    __syncthreads();
    h[t] = excl;
    __syncthreads();
    for (int i = lo + t; i < hi; i += 256) {
        uint p = pairs[i];
        int ld = p & 255u;
        int o = atomicAdd(&h[ld], 1);
        nbr[lo + o] = (int)(p >> 8);
    }
}

// ---------- fp32 -> packed bf16 table (layer 0 input) ----------
__global__ __launch_bounds__(256) void to_bf16_kernel(const float* __restrict__ in,
                                                      uint* __restrict__ table, int n8) {
    int i = blockIdx.x * blockDim.x + threadIdx.x;
    if (i >= n8) return;
    float4 a = *(const float4*)&in[(size_t)i * 8];
    float4 b = *(const float4*)&in[(size_t)i * 8 + 4];
    uint4 p = make_uint4(pack_bf16_rne(a.x, a.y), pack_bf16_rne(a.z, a.w),
                         pack_bf16_rne(b.x, b.y), pack_bf16_rne(b.z, b.w));
    *(uint4*)&table[(size_t)i * 4] = p;
}

// reduce NSLOT-slotted sums -> BN scale/shift (1 block; ~1us launch, measured r10)
__global__ void finalize_kernel(const float* __restrict__ sums, const float* __restrict__ g,
                                const float* __restrict__ be, float* __restrict__ scale,
                                float* __restrict__ shift, int C, float invN) {
    int d = threadIdx.x;
    if (d >= C) return;
    float s = 0.0f, s2 = 0.0f;
    for (int k = 0; k < NSLOT; k++) {
        s += sums[k * 2 * C + d];
        s2 += sums[k * 2 * C + C + d];
    }
    float mean = s * invN;
    float var = s2 * invN - mean * mean;
    float sc = g[d] * rsqrtf(var + 1e-5f);
    scale[d] = sc;
    shift[d] = be[d] - mean * sc;
}

// ---------- aggregation: one 64-lane wave per node; packed-bf16 in and out ----------
template <bool ACT>
__global__ __launch_bounds__(256) void gather_kernel(
    const uint* __restrict__ tb, const int* __restrict__ ptr, const int* __restrict__ cnt,
    const int* __restrict__ nbr, const float* __restrict__ eps_gin, int layer,
    const float* __restrict__ scale, const float* __restrict__ shift, uint* __restrict__ agg,
    int N) {
    int gtid = blockIdx.x * blockDim.x + threadIdx.x;
    int node = gtid >> 6;
    if (node >= N) return;
    int lane = threadIdx.x & 63;
    int half = lane >> 5;
    int sl = lane & 31;
    float sc0 = 1.0f, sh0 = 0.0f, sc1 = 1.0f, sh1 = 0.0f;
    if (ACT) {
        sc0 = scale[2 * sl + 0];
        sh0 = shift[2 * sl + 0];
        sc1 = scale[2 * sl + 1];
        sh1 = shift[2 * sl + 1];
    }
    int start = ptr[node];
    int deg = cnt[node];
    float a0 = 0.0f, a1 = 0.0f;
    int j = half;
    for (; j + 14 < deg; j += 16) {  // 8 independent row loads per half
        int ni[8];
        uint vv[8];
#pragma unroll
        for (int q = 0; q < 8; q++) ni[q] = nbr[start + j + 2 * q];
#pragma unroll
        for (int q = 0; q < 8; q++) vv[q] = tb[(size_t)ni[q] * 32 + sl];
#pragma unroll
        for (int q = 0; q < 8; q++) {
            float f0 = UAF(vv[q] << 16), f1 = UAF(vv[q] & 0xffff0000u);
            if (ACT) {
                f0 = LRELU(f0 * sc0 + sh0);
                f1 = LRELU(f1 * sc1 + sh1);
            }
            a0 += f0;
            a1 += f1;
        }
    }
    for (; j + 6 < deg; j += 8) {
        int ni[4];
        uint vv[4];
#pragma unroll
        for (int q = 0; q < 4; q++) ni[q] = nbr[start + j + 2 * q];
#pragma unroll
        for (int q = 0; q < 4; q++) vv[q] = tb[(size_t)ni[q] * 32 + sl];
#pragma unroll
        for (int q = 0; q < 4; q++) {
            float f0 = UAF(vv[q] << 16), f1 = UAF(vv[q] & 0xffff0000u);
            if (ACT) {
                f0 = LRELU(f0 * sc0 + sh0);
                f1 = LRELU(f1 * sc1 + sh1);
            }
            a0 += f0;
            a1 += f1;
        }
    }
    for (; j < deg; j += 2) {
        uint vA = tb[(size_t)nbr[start + j] * 32 + sl];
        float f0 = UAF(vA << 16), f1 = UAF(vA & 0xffff0000u);
        if (ACT) {
            f0 = LRELU(f0 * sc0 + sh0);
            f1 = LRELU(f1 * sc1 + sh1);
        }
        a0 += f0;
        a1 += f1;
    }
    a0 += __shfl(a0, lane ^ 32);
    a1 += __shfl(a1, lane ^ 32);
    uint vs = tb[(size_t)node * 32 + sl];
    float s0 = UAF(vs << 16), s1 = UAF(vs & 0xffff0000u);
    if (ACT) {
        s0 = LRELU(s0 * sc0 + sh0);
        s1 = LRELU(s1 * sc1 + sh1);
    }
    float ep = 1.0f + eps_gin[layer];
    a0 += ep * s0;
    a1 += ep * s1;
    if (half == 0) agg[(size_t)node * 32 + sl] = pack_bf16_rne(a0, a1);
}

// ---------- bf16-dot gemm (COLS=64): input packed bf16 (agg) or fp32+BN (h1, packed once);
// output bf16 table or fp32; stats into NSLOT-spread atomics (slot = blockIdx&15) ----------
template <bool INBN, bool OUTB, int MINW>
__global__ __launch_bounds__(256, MINW) void gemm_bf16_kernel(
    const uint* __restrict__ inb, const float* __restrict__ inf, const float* __restrict__ W,
    const float* __restrict__ bias, const float* __restrict__ scale,
    const float* __restrict__ shift, uint* __restrict__ outb, float* __restrict__ outf,
    float* __restrict__ sums, int nrows) {
    constexpr int COLS = 64;
    __shared__ uint smem[32 * 68 + 32 * COLS];
    uint* inT = smem;
    uint* wsb = smem + 32 * 68;
    int t = threadIdx.x;
    int row0 = blockIdx.x * 64;

    if (!INBN) {
        for (int i = 0; i < 2; i++) {
            int f = t + 256 * i;
            int r = f >> 3, q = f & 7;
            int gr = row0 + r;
            uint4 v = make_uint4(0, 0, 0, 0);
            if (gr < nrows) v = *(const uint4*)&inb[(size_t)gr * 32 + q * 4];
            inT[(4 * q + 0) * 68 + r] = v.x;
            inT[(4 * q + 1) * 68 + r] = v.y;
            inT[(4 * q + 2) * 68 + r] = v.z;
            inT[(4 * q + 3) * 68 + r] = v.w;
        }
    } else {
        for (int i = 0; i < 4; i++) {
            int f = t + 256 * i;
            int r = f >> 4, q = f & 15;
            int gr = row0 + r;
            float4 v = make_float4(0.f, 0.f, 0.f, 0.f);
            if (gr < nrows) v = *(const float4*)&inf[(size_t)gr * 64 + q * 4];
            int d = 4 * q;
            float e0 = LRELU(v.x * scale[d + 0] + shift[d + 0]);
            float e1 = LRELU(v.y * scale[d + 1] + shift[d + 1]);
            float e2 = LRELU(v.z * scale[d + 2] + shift[d + 2]);
            float e3 = LRELU(v.w * scale[d + 3] + shift[d + 3]);
            inT[(2 * q + 0) * 68 + r] = pack_bf16_rne(e0, e1);
            inT[(2 * q + 1) * 68 + r] = pack_bf16_rne(e2, e3);
        }
    }
    for (int i = 0; i < COLS / 8; i++) {
        int f = t + 256 * i;
        int kp = f / COLS, c = f % COLS;
        wsb[kp * COLS + c] =
            pack_bf16_rne(W[(size_t)(2 * kp) * COLS + c], W[(size_t)(2 * kp + 1) * COLS + c]);
    }
    __syncthreads();

    int rg = t >> 4, cg = t & 15;
    int r0 = rg * 4, c0 = cg * 4;
    float acc[4][4];
#pragma unroll
    for (int r = 0; r < 4; r++)
#pragma unroll
        for (int c = 0; c < 4; c++) acc[r][c] = 0.0f;

#pragma unroll 8
    for (int kp = 0; kp < 32; kp++) {
        uint4 a = *(const uint4*)&inT[kp * 68 + r0];
        uint av[4] = {a.x, a.y, a.z, a.w};
        uint4 w = *(const uint4*)&wsb[kp * COLS + c0];
        uint wv[4] = {w.x, w.y, w.z, w.w};
#pragma unroll
        for (int r = 0; r < 4; r++)
#pragma unroll
            for (int c = 0; c < 4; c++) acc[r][c] = dot2bf(av[r], wv[c], acc[r][c]);
    }

    float ps[4], ps2[4];
#pragma unroll
    for (int c = 0; c < 4; c++) ps[c] = ps2[c] = 0.0f;
    float4 bv = *(const float4*)&bias[c0];
#pragma unroll
    for (int r = 0; r < 4; r++) {
        int gr = row0 + r0 + r;
        if (gr < nrows) {
            float o0 = acc[r][0] + bv.x;
            float o1 = acc[r][1] + bv.y;
            float o2 = acc[r][2] + bv.z;
            float o3 = acc[r][3] + bv.w;
            if (OUTB) {
                uint2 pk = make_uint2(pack_bf16_rne(o0, o1), pack_bf16_rne(o2, o3));
                *(uint2*)&outb[(size_t)gr * 32 + (c0 >> 1)] = pk;
            } else {
                *(float4*)&outf[(size_t)gr * 64 + c0] = make_float4(o0, o1, o2, o3);
            }
            ps[0] += o0;
            ps2[0] += o0 * o0;
            ps[1] += o1;
            ps2[1] += o1 * o1;
            ps[2] += o2;
            ps2[2] += o2 * o2;
            ps[3] += o3;
            ps2[3] += o3 * o3;
        }
    }

    if (sums == nullptr) return;

    __syncthreads();
    float* red = (float*)smem;
    float* red2 = red + 16 * COLS;
    *(float4*)&red[rg * COLS + c0] = *(float4*)&ps[0];
    *(float4*)&red2[rg * COLS + c0] = *(float4*)&ps2[0];
    __syncthreads();
    if (t < COLS) {
        float s = 0.0f, s2 = 0.0f;
#pragma unroll
        for (int j = 0; j < 16; j++) {
            s += red[j * COLS + t];
            s2 += red2[j * COLS + t];
        }
        int slot = blockIdx.x & (NSLOT - 1);
        atomicAdd(&sums[slot * 2 * COLS + t], s);
        atomicAdd(&sums[slot * 2 * COLS + COLS + t], s2);
    }
}

// ---------- head gemm, full fp32: HF = X @ Wf1 + bf1, slotted col-stats ----------
__global__ __launch_bounds__(256, 4) void gemm_f32_head_kernel(const float* __restrict__ in,
                                                               const float* __restrict__ W,
                                                               const float* __restrict__ bias,
                                                               float* __restrict__ out,
                                                               float* __restrict__ sums,
                                                               int nrows) {
    constexpr int COLS = 128;
    __shared__ float inT[64][68];
    __shared__ float ws[64][COLS];
    int t = threadIdx.x;
    int row0 = blockIdx.x * 64;

    for (int i = 0; i < 4; i++) {
        int f = t + 256 * i;
        int r = f >> 4, ch = f & 15;
        int gr = row0 + r;
        float4 v = make_float4(0.f, 0.f, 0.f, 0.f);
        if (gr < nrows) v = *(const float4*)&in[(size_t)gr * 64 + ch * 4];
        inT[ch * 4 + 0][r] = v.x;
        inT[ch * 4 + 1][r] = v.y;
        inT[ch * 4 + 2][r] = v.z;
        inT[ch * 4 + 3][r] = v.w;
    }
    for (int i = 0; i < COLS / 16; i++) {
        int f = t + 256 * i;
        int k = f / (COLS / 4), c4 = f % (COLS / 4);
        *(float4*)&ws[k][c4 * 4] = *(const float4*)&W[(size_t)k * COLS + c4 * 4];
    }
    __syncthreads();

    int rg = t >> 4, cg = t & 15;
    int r0 = rg * 4, c0 = cg * 4;
    float acc[4][8];
#pragma unroll
    for (int r = 0; r < 4; r++)
#pragma unroll
        for (int c = 0; c < 8; c++) acc[r][c] = 0.0f;

#pragma unroll 16
    for (int k = 0; k < 64; k++) {
        float4 a = *(const float4*)&inT[k][r0];
        float ar[4] = {a.x, a.y, a.z, a.w};
#pragma unroll
        for (int jj = 0; jj < 2; jj++) {
            float4 w4 = *(const float4*)&ws[k][c0 + jj * 64];
            float wr[4] = {w4.x, w4.y, w4.z, w4.w};
#pragma unroll
            for (int r = 0; r < 4; r++)
#pragma unroll
                for (int c = 0; c < 4; c++) acc[r][jj * 4 + c] += ar[r] * wr[c];
        }
    }

    float ps[8], ps2[8];
#pragma unroll
    for (int c = 0; c < 8; c++) ps[c] = ps2[c] = 0.0f;
#pragma unroll
    for (int r = 0; r < 4; r++) {
        int gr = row0 + r0 + r;
        if (gr < nrows) {
#pragma unroll
            for (int jj = 0; jj < 2; jj++) {
                float4 bv = *(const float4*)&bias[c0 + jj * 64];
                float4 o = make_float4(acc[r][jj * 4 + 0] + bv.x, acc[r][jj * 4 + 1] + bv.y,
                                       acc[r][jj * 4 + 2] + bv.z, acc[r][jj * 4 + 3] + bv.w);
                *(float4*)&out[(size_t)gr * COLS + c0 + jj * 64] = o;
                ps[jj * 4 + 0] += o.x;
                ps2[jj * 4 + 0] += o.x * o.x;
                ps[jj * 4 + 1] += o.y;
                ps2[jj * 4 + 1] += o.y * o.y;
                ps[jj * 4 + 2] += o.z;
                ps2[jj * 4 + 2] += o.z * o.z;
                ps[jj * 4 + 3] += o.w;
                ps2[jj * 4 + 3] += o.w * o.w;
            }
        }
    }

    __syncthreads();
    float* red = &inT[0][0];
    float* red2 = red + 16 * COLS;
#pragma unroll
    for (int jj = 0; jj < 2; jj++) {
        *(float4*)&red[rg * COLS + c0 + jj * 64] = *(float4*)&ps[jj * 4];
        *(float4*)&red2[rg * COLS + c0 + jj * 64] = *(float4*)&ps2[jj * 4];
    }
    __syncthreads();
    if (t < COLS) {
        float s = 0.0f, s2 = 0.0f;
#pragma unroll
        for (int j = 0; j < 16; j++) {
            s += red[j * COLS + t];
            s2 += red2[j * COLS + t];
        }
        int slot = blockIdx.x & (NSLOT - 1);
        atomicAdd(&sums[slot * 2 * COLS + t], s);
        atomicAdd(&sums[slot * 2 * COLS + COLS + t], s2);
    }
}

// one wave per row; hf fp32 (N x 128)
__global__ void head_out_kernel(const float* __restrict__ hf, const float* __restrict__ scale,
                                const float* __restrict__ shift, const float* __restrict__ Wf2,
                                const float* __restrict__ bf2, float* __restrict__ out,
                                int nrows) {
    int gtid = blockIdx.x * blockDim.x + threadIdx.x;
    int wid = gtid >> 6;
    int l = threadIdx.x & 63;
    if (wid >= nrows) return;
    float v0 = hf[(size_t)wid * 128 + l];
    float v1 = hf[(size_t)wid * 128 + 64 + l];
    v0 = LRELU(v0 * scale[l] + shift[l]);
    v1 = LRELU(v1 * scale[64 + l] + shift[64 + l]);
    float p = v0 * Wf2[l] + v1 * Wf2[64 + l];
    for (int o = 32; o > 0; o >>= 1) p += __shfl_down(p, o);
    if (l == 0) out[wid] = p + bf2[0];
}

extern "C" void kernel_launch(void* const* d_in, const int* in_sizes, int n_in, void* d_out,
                              int out_size, void* d_ws, size_t ws_size, hipStream_t stream) {
    const float* x = (const float*)d_in[0];
    const int* esrc = (const int*)d_in[1];
    const int* edst = (const int*)d_in[2];
    const float* W1 = (const float*)d_in[3];
    const float* b1 = (const float*)d_in[4];
    const float* g1 = (const float*)d_in[5];
    const float* be1 = (const float*)d_in[6];
    const float* W2 = (const float*)d_in[7];
    const float* b2 = (const float*)d_in[8];
    const float* eps_gin = (const float*)d_in[9];
    const float* g_bn = (const float*)d_in[10];
    const float* b_bn = (const float*)d_in[11];
    const float* Wf1 = (const float*)d_in[12];
    const float* bf1 = (const float*)d_in[13];
    const float* gf = (const float*)d_in[14];
    const float* bef = (const float*)d_in[15];
    const float* Wf2 = (const float*)d_in[16];
    const float* bf2 = (const float*)d_in[17];
    float* out = (float*)d_out;

    int N = in_sizes[0] / 64;
    int E = in_sizes[1];
    int NB = (N + 255) / 256;
    float invN = 1.0f / (float)N;

    float* ws = (float*)d_ws;
    size_t ND = (size_t)N * 64;
    // region A: table bf16 (lower half) + pairs (upper, build-only); later X fp32 (full)
    uint* table = (uint*)ws;
    uint* pairs = (uint*)(ws + ND / 2);
    float* X = ws;
    float* h1 = ws + ND;               // region B: h1 fp32
    uint* agg = (uint*)(ws + 2 * ND);  // region C: agg bf16 (lower half)
    float* HF = ws + ND;               // HF fp32 spans B+C after h1/agg dead
    float* stats = ws + 3 * ND;
    // slotted sums: 5 sets of NSLOT*128 (C=64) + 1 head set of NSLOT*256 (C=128)
    // set k (k<5) at stats + k*NSLOT*128; head at stats + 5*NSLOT*128
    float* ssarea = stats + 5 * NSLOT * 128 + NSLOT * 256;  // scale/shift: 5*128 + 256
    int* ibase = (int*)(ssarea + 5 * 128 + 256);
    int* bcnt = ibase;
    int* bcur = ibase + 512;
    int* boff = ibase + 1024;
    int* cnt = ibase + 1536;
    int* ptr = cnt + N;
    int* nbr = ptr + N;

    int nzero = 5 * NSLOT * 128 + NSLOT * 256 + 5 * 128 + 256 + 512;  // sums+ss+bcnt
    zero_kernel<<<(nzero + 255) / 256, 256, 0, stream>>>(stats, nzero);

    int eb = (E + 8191) / 8192;
    bhist_kernel<<<eb, 256, 0, stream>>>(edst, bcnt, E, NB);
    bscan_kernel<<<1, 512, 0, stream>>>(bcnt, boff, bcur, NB);
    bscatter_kernel<<<eb, 256, 0, stream>>>(esrc, edst, bcur, pairs, E, NB);
    bcsr_kernel<<<NB, 256, 0, stream>>>(pairs, boff, ptr, cnt, nbr, N, NB, E);

    int n8 = N * 8;
    int gg = (N + 63) / 64;
    int gblocks = (N * 64 + 255) / 256;
    to_bf16_kernel<<<(n8 + 255) / 256, 256, 0, stream>>>(x, table, n8);

    for (int i = 0; i < 3; i++) {
        float* st = stats + (size_t)(2 * i) * NSLOT * 128;      // inner sums (slotted)
        float* so = stats + (size_t)(2 * i + 1) * NSLOT * 128;  // outer sums (layers 0,1)
        float* st_ss = ssarea + (size_t)(2 * i) * 128;          // inner scale/shift
        float* so_ss = ssarea + (size_t)(2 * i + 1) * 128;      // outer scale/shift
        if (i == 0) {
            gather_kernel<false><<<gblocks, 256, 0, stream>>>(table, ptr, cnt, nbr, eps_gin, i,
                                                              nullptr, nullptr, agg, N);
        } else {
            float* sp_ss = ssarea + (size_t)(2 * (i - 1) + 1) * 128;
            gather_kernel<true><<<gblocks, 256, 0, stream>>>(table, ptr, cnt, nbr, eps_gin, i,
                                                             sp_ss, sp_ss + 64, agg, N);
        }
        // gemm1: agg(bf16) @ W1 -> h1 fp32 (+slotted inner stats)
        gemm_bf16_kernel<false, false, 6><<<gg, 256, 0, stream>>>(
            agg, nullptr, W1 + (size_t)i * 4096, b1 + (size_t)i * 64, nullptr, nullptr, nullptr,
            h1, st, N);
        finalize_kernel<<<1, 64, 0, stream>>>(st, g1 + (size_t)i * 64, be1 + (size_t)i * 64,
                                              st_ss, st_ss + 64, 64, invN);
        // gemm2: BN(h1)+lrelu packed once -> @ W2 -> table bf16 (L0,1) / X fp32 (L2)
        if (i < 2) {
            gemm_bf16_kernel<true, true, 6><<<gg, 256, 0, stream>>>(
                nullptr, h1, W2 + (size_t)i * 4096, b2 + (size_t)i * 64, st_ss, st_ss + 64,
                table, nullptr, so, N);
            finalize_kernel<<<1, 64, 0, stream>>>(so, g_bn + (size_t)i * 64,
                                                  b_bn + (size_t)i * 64, so_ss, so_ss + 64, 64,
                                                  invN);
        } else {
            gemm_bf16_kernel<true, false, 6><<<gg, 256, 0, stream>>>(
                nullptr, h1, W2 + (size_t)i * 4096, b2 + (size_t)i * 64, st_ss, st_ss + 64,
                nullptr, X, nullptr, N);
        }
    }

    float* sf = stats + (size_t)5 * NSLOT * 128;  // head slotted sums (C=128)
    float* sf_ss = ssarea + 5 * 128;              // head scale/shift (256)
    gemm_f32_head_kernel<<<gg, 256, 0, stream>>>(X, Wf1, bf1, HF, sf, N);
    finalize_kernel<<<1, 128, 0, stream>>>(sf, gf, bef, sf_ss, sf_ss + 128, 128, invN);
    head_out_kernel<<<(N + 3) / 4, 256, 0, stream>>>(HF, sf_ss, sf_ss + 128, Wf2, bf2, out, N);
}